// Round 2
// baseline (668.954 us; speedup 1.0000x reference)
//
#include <hip/hip_runtime.h>

typedef unsigned short u16;
typedef __attribute__((ext_vector_type(8))) short bf16x8_t;   // 8 bf16 (4 VGPRs)
typedef __attribute__((ext_vector_type(4))) float f32x4_t;
typedef __attribute__((ext_vector_type(4))) unsigned short u16x4_t;

#define H_DIM 1024
#define NH 16
#define DH 64
#define I_DIM 4096
#define BATCH 4
#define SEQ 1024
#define M_ROWS 4096   /* BATCH*SEQ */

__device__ __forceinline__ u16 f2bf(float f) {
    unsigned int u = __builtin_bit_cast(unsigned int, f);
    u += 0x7fffu + ((u >> 16) & 1u);
    return (u16)(u >> 16);
}

__device__ __forceinline__ void gld16(const void* g, void* l) {
    __builtin_amdgcn_global_load_lds(
        (const __attribute__((address_space(1))) unsigned int*)g,
        (__attribute__((address_space(3))) unsigned int*)l,
        16, 0, 0);
}

// ---------------- routing: per-token Gram + scalar t-loop -> c1,c2 ----------------
__global__ void routing_kernel(const float* __restrict__ x, const float* __restrict__ y,
                               const int* __restrict__ tptr,
                               float* __restrict__ c1o, float* __restrict__ c2o)
{
    int tok  = blockIdx.x * 4 + (threadIdx.x >> 6);
    int lane = threadIdx.x & 63;
    const f32x4_t* xp = (const f32x4_t*)(x + (size_t)tok * H_DIM);
    const f32x4_t* yp = (const f32x4_t*)(y + (size_t)tok * H_DIM);
    float xx = 0.f, xy = 0.f, yy = 0.f;
#pragma unroll
    for (int k = 0; k < 4; ++k) {
        f32x4_t xv = xp[k * 64 + lane], yv = yp[k * 64 + lane];
#pragma unroll
        for (int e = 0; e < 4; ++e) { xx += xv[e]*xv[e]; xy += xv[e]*yv[e]; yy += yv[e]*yv[e]; }
    }
#pragma unroll
    for (int m = 32; m; m >>= 1) {
        xx += __shfl_xor(xx, m); xy += __shfl_xor(xy, m); yy += __shfl_xor(yy, m);
    }
    int T = tptr[0];
    float c1 = 0.5f, c2 = 0.5f, b1 = 0.f, b2 = 0.f;
    for (int i = 0; i < T; ++i) {
        if (i > 0) {
            float mx = fmaxf(b1, b2);
            float e1 = __expf(b1 - mx), e2 = __expf(b2 - mx);
            float inv = 1.0f / (e1 + e2);
            c1 = e1 * inv; c2 = e2 * inv;
        }
        float vv = c1*c1*xx + 2.0f*c1*c2*xy + c2*c2*yy;
        float n  = sqrtf(vv);
        float s  = n / (1.0f + vv);            // n/(1+n^2), n^2 == vv
        float d1 = s * (c1*xx + c2*xy);
        float d2 = s * (c1*xy + c2*yy);
        b1 += d1; b2 += d2;
    }
    if (lane == 0) { c1o[tok] = c1; c2o[tok] = c2; }
}

// ---------------- xs = bf16(c1*x), ys = bf16(c2*y) ----------------
__global__ void scale_cast_kernel(const float* __restrict__ x, const float* __restrict__ y,
                                  const float* __restrict__ c1, const float* __restrict__ c2,
                                  u16* __restrict__ xs, u16* __restrict__ ys)
{
    int i = blockIdx.x * 256 + threadIdx.x;   // float4 index; one row per block
    int row = i >> 8;
    float a = c1[row], b = c2[row];
    f32x4_t xv = ((const f32x4_t*)x)[i], yv = ((const f32x4_t*)y)[i];
    u16x4_t xo, yo;
#pragma unroll
    for (int e = 0; e < 4; ++e) { xo[e] = f2bf(xv[e]*a); yo[e] = f2bf(yv[e]*b); }
    ((u16x4_t*)xs)[i] = xo;
    ((u16x4_t*)ys)[i] = yo;
}

// ---------------- W (Kw x Nw) f32 -> W^T (Nw x Kw) bf16 ----------------
__global__ void wcast_kernel(const float* __restrict__ W, u16* __restrict__ Wt, int Kw, int Nw)
{
    __shared__ float t[32][33];
    int nbj = Nw >> 5;
    int bi = blockIdx.x / nbj, bj = blockIdx.x % nbj;
    int tid = threadIdx.x;
#pragma unroll
    for (int p = 0; p < 4; ++p) {
        int idx = p * 256 + tid;
        int r = idx >> 5, c = idx & 31;
        t[r][c] = W[(size_t)(bi*32 + r) * Nw + bj*32 + c];
    }
    __syncthreads();
#pragma unroll
    for (int p = 0; p < 4; ++p) {
        int idx = p * 256 + tid;
        int r = idx >> 5, c = idx & 31;
        Wt[(size_t)(bj*32 + r) * Kw + bi*32 + c] = f2bf(t[c][r]);
    }
}

// ---------------- GEMM: C = A(M,K) @ Bt(N,K)^T, bf16 in, f32 accum ----------------
// epi 0: outb = bf16((acc+bias)*scale)
// epi 1: outf = acc + bias + (rscale?rscale[row]:1)*resm[row,col]
// epi 2: outb = bf16(gelu_exact(acc+bias))
#define BM 128
#define BN 128
#define BK 64

__global__ __launch_bounds__(256, 2) void gemm_bt(
    const u16* __restrict__ A, const u16* __restrict__ Bt, int N, int K,
    const float* __restrict__ bias, float scale, int epi,
    u16* __restrict__ outb, float* __restrict__ outf,
    const float* __restrict__ rscale, const float* __restrict__ resm)
{
    __shared__ u16 As[BM * BK];   // 16KB, row-major 128x64
    __shared__ u16 Bs[BN * BK];   // 16KB
    const int ntN = N / BN;
    const int tm = blockIdx.x / ntN, tn = blockIdx.x % ntN;
    const int tid = threadIdx.x;
    const int w = tid >> 6, lane = tid & 63, q4 = lane >> 4, l16 = lane & 15;
    const int wm = (w >> 1) * 64, wn = (w & 1) * 64;

    // staging map: chunk c covers rows c*32..c*32+31; thread -> row tid>>3, col (tid&7)*8
    const int srow = tid >> 3;
    const int scol = (tid & 7) * 8;
    const u16* ga = A  + (size_t)(tm * BM + srow) * K + scol;
    const u16* gb = Bt + (size_t)(tn * BN + srow) * K + scol;

    f32x4_t acc[4][4];
#pragma unroll
    for (int mt = 0; mt < 4; ++mt)
#pragma unroll
        for (int nt = 0; nt < 4; ++nt) acc[mt][nt] = (f32x4_t){0.f,0.f,0.f,0.f};

    for (int k0 = 0; k0 < K; k0 += BK) {
        __syncthreads();
#pragma unroll
        for (int c = 0; c < 4; ++c) {
            gld16(ga + (size_t)c * 32 * K + k0, &As[c * 2048 + w * 512]);
            gld16(gb + (size_t)c * 32 * K + k0, &Bs[c * 2048 + w * 512]);
        }
        __syncthreads();
#pragma unroll
        for (int kc = 0; kc < 2; ++kc) {
            bf16x8_t af[4], bfr[4];
#pragma unroll
            for (int mt = 0; mt < 4; ++mt)
                af[mt] = *(const bf16x8_t*)&As[(wm + mt*16 + l16) * BK + kc*32 + q4*8];
#pragma unroll
            for (int nt = 0; nt < 4; ++nt)
                bfr[nt] = *(const bf16x8_t*)&Bs[(wn + nt*16 + l16) * BK + kc*32 + q4*8];
#pragma unroll
            for (int mt = 0; mt < 4; ++mt)
#pragma unroll
                for (int nt = 0; nt < 4; ++nt)
                    acc[mt][nt] = __builtin_amdgcn_mfma_f32_16x16x32_bf16(af[mt], bfr[nt], acc[mt][nt], 0, 0, 0);
        }
    }

#pragma unroll
    for (int mt = 0; mt < 4; ++mt) {
#pragma unroll
        for (int nt = 0; nt < 4; ++nt) {
            const int gcol = tn * BN + wn + nt*16 + l16;
            const float bv = bias[gcol];
#pragma unroll
            for (int r = 0; r < 4; ++r) {
                const int grow = tm * BM + wm + mt*16 + q4*4 + r;
                const size_t oidx = (size_t)grow * N + gcol;
                float v = acc[mt][nt][r] + bv;
                if (epi == 0) {
                    outb[oidx] = f2bf(v * scale);
                } else if (epi == 1) {
                    float rs = rscale ? rscale[grow] : 1.0f;
                    outf[oidx] = v + rs * resm[oidx];
                } else {
                    float g = 0.5f * v * (1.0f + erff(v * 0.70710678118f));
                    outb[oidx] = f2bf(g);
                }
            }
        }
    }
}

// ---------------- V (B,S,NH,DH) bf16 -> Vt (B,NH,DH,S) bf16 ----------------
__global__ void vtrans_kernel(const u16* __restrict__ vb, u16* __restrict__ vt)
{
    __shared__ u16 t[64][65];
    const int blk = blockIdx.x;
    const int st = blk & 15, h = (blk >> 4) & 15, b = blk >> 8;
    const int tid = threadIdx.x;
#pragma unroll
    for (int p = 0; p < 16; ++p) {
        int idx = p * 256 + tid;
        int s = idx >> 6, d = idx & 63;
        t[s][d] = vb[(size_t)(b*SEQ + st*64 + s) * H_DIM + h*DH + d];
    }
    __syncthreads();
#pragma unroll
    for (int p = 0; p < 16; ++p) {
        int idx = p * 256 + tid;
        int d = idx >> 6, s = idx & 63;
        vt[(size_t)((b*NH + h)*DH + d) * SEQ + st*64 + s] = t[s][d];
    }
}

// ---------------- flash attention: Br=64 (4 waves x 16 rows), Bc=64 ----------------
__global__ __launch_bounds__(256) void attn_kernel(
    const u16* __restrict__ qb, const u16* __restrict__ kb,
    const u16* __restrict__ vt, const float* __restrict__ mask,
    u16* __restrict__ ctx)
{
    __shared__ u16 plds[4][16 * 80];   // per-wave P tile, stride 80 (160B rows, 16B aligned)
    const int blk = blockIdx.x;
    const int qt = blk & 15, h = (blk >> 4) & 15, b = blk >> 8;
    const int tid = threadIdx.x, w = tid >> 6, lane = tid & 63, q4 = lane >> 4, l16 = lane & 15;

    const u16* qrow = qb + ((size_t)(b*SEQ + qt*64 + w*16 + l16) * H_DIM + h*DH);
    bf16x8_t qf0 = *(const bf16x8_t*)(qrow + q4*8);
    bf16x8_t qf1 = *(const bf16x8_t*)(qrow + 32 + q4*8);

    f32x4_t o[4];
#pragma unroll
    for (int dt = 0; dt < 4; ++dt) o[dt] = (f32x4_t){0.f,0.f,0.f,0.f};
    float mi[4] = {-1e30f,-1e30f,-1e30f,-1e30f};
    float li[4] = {0.f,0.f,0.f,0.f};
    u16* pw = &plds[w][0];

    for (int j = 0; j < 16; ++j) {
        const int kbase = j * 64;
        f32x4_t sc[4];
#pragma unroll
        for (int nt = 0; nt < 4; ++nt) {
            const int kr = kbase + nt*16 + l16;
            const u16* krow = kb + ((size_t)(b*SEQ + kr) * H_DIM + h*DH);
            bf16x8_t kf0 = *(const bf16x8_t*)(krow + q4*8);
            bf16x8_t kf1 = *(const bf16x8_t*)(krow + 32 + q4*8);
            f32x4_t s = (f32x4_t){0.f,0.f,0.f,0.f};
            s = __builtin_amdgcn_mfma_f32_16x16x32_bf16(qf0, kf0, s, 0, 0, 0);
            s = __builtin_amdgcn_mfma_f32_16x16x32_bf16(qf1, kf1, s, 0, 0, 0);
            const float mv = mask[b*SEQ + kr];
            s[0] += mv; s[1] += mv; s[2] += mv; s[3] += mv;
            sc[nt] = s;
        }
        float rm[4], al[4], rs[4];
#pragma unroll
        for (int r = 0; r < 4; ++r)
            rm[r] = fmaxf(fmaxf(sc[0][r], sc[1][r]), fmaxf(sc[2][r], sc[3][r]));
#pragma unroll
        for (int d = 1; d < 16; d <<= 1)
#pragma unroll
            for (int r = 0; r < 4; ++r) rm[r] = fmaxf(rm[r], __shfl_xor(rm[r], d));
#pragma unroll
        for (int r = 0; r < 4; ++r) {
            float nm = fmaxf(mi[r], rm[r]);
            al[r] = __expf(mi[r] - nm);
            mi[r] = nm; rs[r] = 0.f;
        }
#pragma unroll
        for (int nt = 0; nt < 4; ++nt)
#pragma unroll
            for (int r = 0; r < 4; ++r) {
                float p = __expf(sc[nt][r] - mi[r]);
                sc[nt][r] = p; rs[r] += p;
            }
#pragma unroll
        for (int d = 1; d < 16; d <<= 1)
#pragma unroll
            for (int r = 0; r < 4; ++r) rs[r] += __shfl_xor(rs[r], d);
#pragma unroll
        for (int r = 0; r < 4; ++r) li[r] = li[r] * al[r] + rs[r];
#pragma unroll
        for (int dt = 0; dt < 4; ++dt)
#pragma unroll
            for (int r = 0; r < 4; ++r) o[dt][r] *= al[r];
        // P (C-layout) -> LDS -> A-layout frags
#pragma unroll
        for (int nt = 0; nt < 4; ++nt)
#pragma unroll
            for (int r = 0; r < 4; ++r)
                pw[(q4*4 + r) * 80 + nt*16 + l16] = f2bf(sc[nt][r]);
        __syncthreads();
        bf16x8_t pf0 = *(const bf16x8_t*)(pw + l16*80 + q4*8);
        bf16x8_t pf1 = *(const bf16x8_t*)(pw + l16*80 + 32 + q4*8);
#pragma unroll
        for (int dt = 0; dt < 4; ++dt) {
            const u16* vrow = vt + ((size_t)((b*NH + h)*DH + dt*16 + l16) * SEQ + kbase);
            bf16x8_t vf0 = *(const bf16x8_t*)(vrow + q4*8);
            bf16x8_t vf1 = *(const bf16x8_t*)(vrow + 32 + q4*8);
            o[dt] = __builtin_amdgcn_mfma_f32_16x16x32_bf16(pf0, vf0, o[dt], 0, 0, 0);
            o[dt] = __builtin_amdgcn_mfma_f32_16x16x32_bf16(pf1, vf1, o[dt], 0, 0, 0);
        }
        __syncthreads();
    }
    float inv[4];
#pragma unroll
    for (int r = 0; r < 4; ++r) inv[r] = 1.0f / li[r];
#pragma unroll
    for (int dt = 0; dt < 4; ++dt)
#pragma unroll
        for (int r = 0; r < 4; ++r)
            ctx[(size_t)(b*SEQ + qt*64 + w*16 + q4*4 + r) * H_DIM + h*DH + dt*16 + l16]
                = f2bf(o[dt][r] * inv[r]);
}

// ---------------- RMSNorm row kernel: outf = v*rsqrt(mean(v^2)+eps)*g (+ bf16 copy) ----------------
__global__ void rms_kernel(const float* __restrict__ in, const float* __restrict__ g,
                           float* __restrict__ outf, u16* __restrict__ outb)
{
    int row  = blockIdx.x * 4 + (threadIdx.x >> 6);
    int lane = threadIdx.x & 63;
    const f32x4_t* ip = (const f32x4_t*)(in + (size_t)row * H_DIM);
    f32x4_t v[4];
    float ss = 0.f;
#pragma unroll
    for (int k = 0; k < 4; ++k) {
        v[k] = ip[k * 64 + lane];
#pragma unroll
        for (int e = 0; e < 4; ++e) ss += v[k][e] * v[k][e];
    }
#pragma unroll
    for (int m = 32; m; m >>= 1) ss += __shfl_xor(ss, m);
    float sc = rsqrtf(ss * (1.0f / 1024.0f) + 1e-6f);
#pragma unroll
    for (int k = 0; k < 4; ++k) {
        f32x4_t gv = ((const f32x4_t*)g)[k * 64 + lane];
        f32x4_t ov;
        u16x4_t ob;
#pragma unroll
        for (int e = 0; e < 4; ++e) { ov[e] = v[k][e] * sc * gv[e]; ob[e] = f2bf(ov[e]); }
        if (outf) ((f32x4_t*)(outf + (size_t)row * H_DIM))[k * 64 + lane] = ov;
        if (outb) ((u16x4_t*)(outb + (size_t)row * H_DIM))[k * 64 + lane] = ob;
    }
}

extern "C" void kernel_launch(void* const* d_in, const int* in_sizes, int n_in,
                              void* d_out, int out_size, void* d_ws, size_t ws_size,
                              hipStream_t stream)
{
    const float* x   = (const float*)d_in[0];
    const float* y   = (const float*)d_in[1];
    const float* mask= (const float*)d_in[2];
    const float* Wq  = (const float*)d_in[3];
    const float* bq  = (const float*)d_in[4];
    const float* Wk  = (const float*)d_in[5];
    const float* bk  = (const float*)d_in[6];
    const float* Wv  = (const float*)d_in[7];
    const float* bv  = (const float*)d_in[8];
    const float* Wo  = (const float*)d_in[9];
    const float* bo  = (const float*)d_in[10];
    const float* g1  = (const float*)d_in[11];
    const float* Wi  = (const float*)d_in[12];
    const float* bi  = (const float*)d_in[13];
    const float* Wo2 = (const float*)d_in[14];
    const float* bo2 = (const float*)d_in[15];
    const float* g2  = (const float*)d_in[16];
    const int*   tp  = (const int*)d_in[17];
    float* out = (float*)d_out;

    char* ws = (char*)d_ws;
    const size_t MB = 1024 * 1024;
    float* c1    = (float*)(ws);
    float* c2    = (float*)(ws + 16 * 1024);
    u16* xs_b    = (u16*)(ws + 1 * MB);    // 8MB; reused as ctx_b after QKV
    u16* ys_b    = (u16*)(ws + 9 * MB);    // 8MB; reused as att_b after V GEMM
    u16* wq_t    = (u16*)(ws + 17 * MB);
    u16* wk_t    = (u16*)(ws + 19 * MB);
    u16* wv_t    = (u16*)(ws + 21 * MB);
    u16* wo_t    = (u16*)(ws + 23 * MB);
    u16* wi_t    = (u16*)(ws + 25 * MB);   // 8MB
    u16* wo2_t   = (u16*)(ws + 33 * MB);   // 8MB
    u16* qb      = (u16*)(ws + 41 * MB);   // 8MB, reused as inter_b after attention
    u16* kb      = (u16*)(ws + 49 * MB);   // 8MB, ditto
    u16* vb      = (u16*)(ws + 57 * MB);   // 8MB, ditto
    u16* vtb     = (u16*)(ws + 65 * MB);   // 8MB, ditto
    u16* inter_b = qb;
    float* attpre= (float*)(ws + 73 * MB); // 16MB; reused as ffn2 out
    float* attf  = (float*)(ws + 89 * MB); // 16MB
    (void)ws_size; (void)in_sizes; (void)n_in; (void)out_size;

    routing_kernel<<<1024, 256, 0, stream>>>(x, y, tp, c1, c2);
    scale_cast_kernel<<<4096, 256, 0, stream>>>(x, y, c1, c2, xs_b, ys_b);
    wcast_kernel<<<1024, 256, 0, stream>>>(Wq, wq_t, 1024, 1024);
    wcast_kernel<<<1024, 256, 0, stream>>>(Wk, wk_t, 1024, 1024);
    wcast_kernel<<<1024, 256, 0, stream>>>(Wv, wv_t, 1024, 1024);
    wcast_kernel<<<1024, 256, 0, stream>>>(Wo, wo_t, 1024, 1024);
    wcast_kernel<<<4096, 256, 0, stream>>>(Wi, wi_t, 1024, 4096);
    wcast_kernel<<<4096, 256, 0, stream>>>(Wo2, wo2_t, 4096, 1024);

    // Q/K/V projections (1/sqrt(DH)=0.125 folded into Q)
    gemm_bt<<<256, 256, 0, stream>>>(xs_b, wq_t, 1024, 1024, bq, 0.125f, 0, qb, nullptr, nullptr, nullptr);
    gemm_bt<<<256, 256, 0, stream>>>(ys_b, wk_t, 1024, 1024, bk, 1.0f,   0, kb, nullptr, nullptr, nullptr);
    gemm_bt<<<256, 256, 0, stream>>>(ys_b, wv_t, 1024, 1024, bv, 1.0f,   0, vb, nullptr, nullptr, nullptr);
    vtrans_kernel<<<1024, 256, 0, stream>>>(vb, vtb);
    attn_kernel<<<1024, 256, 0, stream>>>(qb, kb, vtb, mask, xs_b /*ctx*/);
    // Wo projection + bias + xs residual (xs = c1*x recomputed in f32)
    gemm_bt<<<256, 256, 0, stream>>>(xs_b, wo_t, 1024, 1024, bo, 1.0f, 1, nullptr, attpre, c1, x);
    rms_kernel<<<1024, 256, 0, stream>>>(attpre, g1, attf, ys_b /*att_b*/);
    // FFN up + exact GELU
    gemm_bt<<<1024, 256, 0, stream>>>(ys_b, wi_t, 4096, 1024, bi, 1.0f, 2, inter_b, nullptr, nullptr, nullptr);
    // FFN down + bias + att residual
    gemm_bt<<<256, 256, 0, stream>>>(inter_b, wo2_t, 1024, 4096, bo2, 1.0f, 1, nullptr, attpre, nullptr, attf);
    rms_kernel<<<1024, 256, 0, stream>>>(attpre, g2, out, nullptr);
}

// Round 3
// 570.163 us; speedup vs baseline: 1.1733x; 1.1733x over previous
//
#include <hip/hip_runtime.h>

typedef unsigned short u16;
typedef __attribute__((ext_vector_type(8))) short bf16x8_t;   // 8 bf16 (4 VGPRs)
typedef __attribute__((ext_vector_type(4))) float f32x4_t;
typedef __attribute__((ext_vector_type(4))) unsigned short u16x4_t;

#define H_DIM 1024
#define NH 16
#define DH 64
#define I_DIM 4096
#define BATCH 4
#define SEQ 1024
#define M_ROWS 4096   /* BATCH*SEQ */

__device__ __forceinline__ u16 f2bf(float f) {
    unsigned int u = __builtin_bit_cast(unsigned int, f);
    u += 0x7fffu + ((u >> 16) & 1u);
    return (u16)(u >> 16);
}

__device__ __forceinline__ void gld16(const void* g, void* l) {
    __builtin_amdgcn_global_load_lds(
        (const __attribute__((address_space(1))) unsigned int*)g,
        (__attribute__((address_space(3))) unsigned int*)l,
        16, 0, 0);
}

// ---------------- routing: per-token Gram + scalar t-loop -> c1,c2 ----------------
__global__ void routing_kernel(const float* __restrict__ x, const float* __restrict__ y,
                               const int* __restrict__ tptr,
                               float* __restrict__ c1o, float* __restrict__ c2o)
{
    int tok  = blockIdx.x * 4 + (threadIdx.x >> 6);
    int lane = threadIdx.x & 63;
    const f32x4_t* xp = (const f32x4_t*)(x + (size_t)tok * H_DIM);
    const f32x4_t* yp = (const f32x4_t*)(y + (size_t)tok * H_DIM);
    float xx = 0.f, xy = 0.f, yy = 0.f;
#pragma unroll
    for (int k = 0; k < 4; ++k) {
        f32x4_t xv = xp[k * 64 + lane], yv = yp[k * 64 + lane];
#pragma unroll
        for (int e = 0; e < 4; ++e) { xx += xv[e]*xv[e]; xy += xv[e]*yv[e]; yy += yv[e]*yv[e]; }
    }
#pragma unroll
    for (int m = 32; m; m >>= 1) {
        xx += __shfl_xor(xx, m); xy += __shfl_xor(xy, m); yy += __shfl_xor(yy, m);
    }
    int T = tptr[0];
    float c1 = 0.5f, c2 = 0.5f, b1 = 0.f, b2 = 0.f;
    for (int i = 0; i < T; ++i) {
        if (i > 0) {
            float mx = fmaxf(b1, b2);
            float e1 = __expf(b1 - mx), e2 = __expf(b2 - mx);
            float inv = 1.0f / (e1 + e2);
            c1 = e1 * inv; c2 = e2 * inv;
        }
        float vv = c1*c1*xx + 2.0f*c1*c2*xy + c2*c2*yy;
        float n  = sqrtf(vv);
        float s  = n / (1.0f + vv);            // n/(1+n^2), n^2 == vv
        float d1 = s * (c1*xx + c2*xy);
        float d2 = s * (c1*xy + c2*yy);
        b1 += d1; b2 += d2;
    }
    if (lane == 0) { c1o[tok] = c1; c2o[tok] = c2; }
}

// ---------------- xs = bf16(c1*x), ys = bf16(c2*y) ----------------
__global__ void scale_cast_kernel(const float* __restrict__ x, const float* __restrict__ y,
                                  const float* __restrict__ c1, const float* __restrict__ c2,
                                  u16* __restrict__ xs, u16* __restrict__ ys)
{
    int i = blockIdx.x * 256 + threadIdx.x;   // float4 index; one row per block
    int row = i >> 8;
    float a = c1[row], b = c2[row];
    f32x4_t xv = ((const f32x4_t*)x)[i], yv = ((const f32x4_t*)y)[i];
    u16x4_t xo, yo;
#pragma unroll
    for (int e = 0; e < 4; ++e) { xo[e] = f2bf(xv[e]*a); yo[e] = f2bf(yv[e]*b); }
    ((u16x4_t*)xs)[i] = xo;
    ((u16x4_t*)ys)[i] = yo;
}

// ---------------- pack two 1024-bias vectors into one 2048 buffer ----------------
__global__ void pack2_kernel(const float* __restrict__ a, const float* __restrict__ b,
                             float* __restrict__ o)
{
    int i = blockIdx.x * 256 + threadIdx.x;   // 0..2047
    o[i] = (i < 1024) ? a[i] : b[i - 1024];
}

// ---------------- W (Kw x Nw) f32 -> W^T (Nw x Kw) bf16 ----------------
__global__ void wcast_kernel(const float* __restrict__ W, u16* __restrict__ Wt, int Kw, int Nw)
{
    __shared__ float t[32][33];
    int nbj = Nw >> 5;
    int bi = blockIdx.x / nbj, bj = blockIdx.x % nbj;
    int tid = threadIdx.x;
#pragma unroll
    for (int p = 0; p < 4; ++p) {
        int idx = p * 256 + tid;
        int r = idx >> 5, c = idx & 31;
        t[r][c] = W[(size_t)(bi*32 + r) * Nw + bj*32 + c];
    }
    __syncthreads();
#pragma unroll
    for (int p = 0; p < 4; ++p) {
        int idx = p * 256 + tid;
        int r = idx >> 5, c = idx & 31;
        Wt[(size_t)(bj*32 + r) * Kw + bi*32 + c] = f2bf(t[c][r]);
    }
}

// ---------------- GEMM: C = A(M,K) @ Bt(N,K)^T, bf16 in, f32 accum ----------------
// epi 0: outb[(gcol>>10)*M*H + grow*H + (gcol&1023)] = bf16((acc+bias)*(gcol<1024?scale:1))
//        (QKV-style split output; for N=1024 it degenerates to a plain store)
// epi 1: outf = acc + bias + (rscale?rscale[row]:1)*resm[row,col]
// epi 2: outb = bf16(gelu_exact(acc+bias))
#define BK 64

template<int TBN>
__global__ __launch_bounds__(256, 2) void gemm_bt(
    const u16* __restrict__ A, const u16* __restrict__ Bt, int N, int K,
    const float* __restrict__ bias, float scale, int epi,
    u16* __restrict__ outb, float* __restrict__ outf,
    const float* __restrict__ rscale, const float* __restrict__ resm)
{
    constexpr int TBM = 128;
    constexpr int MT = (TBN == 128) ? 4 : 2;
    constexpr int NT = 4;
    __shared__ u16 As[TBM * BK];   // 16KB
    __shared__ u16 Bs[TBN * BK];   // 16KB or 8KB
    const int ntN = N / TBN;
    const int tm = blockIdx.x / ntN, tn = blockIdx.x % ntN;
    const int tid = threadIdx.x;
    const int w = tid >> 6, lane = tid & 63, q4 = lane >> 4, l16 = lane & 15;
    const int wm = (TBN == 128) ? (w >> 1) * 64 : w * 32;
    const int wn = (TBN == 128) ? (w & 1) * 64 : 0;

    // staging map: chunk c covers rows c*32..c*32+31; thread -> row tid>>3, col (tid&7)*8
    const int srow = tid >> 3;
    const int scol = (tid & 7) * 8;
    const u16* ga = A  + (size_t)(tm * TBM + srow) * K + scol;
    const u16* gb = Bt + (size_t)(tn * TBN + srow) * K + scol;

    f32x4_t acc[MT][NT];
#pragma unroll
    for (int mt = 0; mt < MT; ++mt)
#pragma unroll
        for (int nt = 0; nt < NT; ++nt) acc[mt][nt] = (f32x4_t){0.f,0.f,0.f,0.f};

    for (int k0 = 0; k0 < K; k0 += BK) {
        __syncthreads();
#pragma unroll
        for (int c = 0; c < 4; ++c)
            gld16(ga + (size_t)c * 32 * K + k0, &As[c * 2048 + w * 512]);
#pragma unroll
        for (int c = 0; c < TBN/32; ++c)
            gld16(gb + (size_t)c * 32 * K + k0, &Bs[c * 2048 + w * 512]);
        __syncthreads();
#pragma unroll
        for (int kc = 0; kc < 2; ++kc) {
            bf16x8_t af[MT], bfr[NT];
#pragma unroll
            for (int mt = 0; mt < MT; ++mt)
                af[mt] = *(const bf16x8_t*)&As[(wm + mt*16 + l16) * BK + kc*32 + q4*8];
#pragma unroll
            for (int nt = 0; nt < NT; ++nt)
                bfr[nt] = *(const bf16x8_t*)&Bs[(wn + nt*16 + l16) * BK + kc*32 + q4*8];
#pragma unroll
            for (int mt = 0; mt < MT; ++mt)
#pragma unroll
                for (int nt = 0; nt < NT; ++nt)
                    acc[mt][nt] = __builtin_amdgcn_mfma_f32_16x16x32_bf16(af[mt], bfr[nt], acc[mt][nt], 0, 0, 0);
        }
    }

#pragma unroll
    for (int mt = 0; mt < MT; ++mt) {
#pragma unroll
        for (int nt = 0; nt < NT; ++nt) {
            const int gcol = tn * TBN + wn + nt*16 + l16;
            const float bv = bias[gcol];
#pragma unroll
            for (int r = 0; r < 4; ++r) {
                const int grow = tm * TBM + wm + mt*16 + q4*4 + r;
                float v = acc[mt][nt][r] + bv;
                if (epi == 0) {
                    float sc2 = (gcol < 1024) ? scale : 1.0f;
                    size_t o = (size_t)(gcol >> 10) * ((size_t)M_ROWS * H_DIM)
                             + (size_t)grow * H_DIM + (gcol & 1023);
                    outb[o] = f2bf(v * sc2);
                } else if (epi == 1) {
                    const size_t oidx = (size_t)grow * N + gcol;
                    float rs = rscale ? rscale[grow] : 1.0f;
                    outf[oidx] = v + rs * resm[oidx];
                } else {
                    const size_t oidx = (size_t)grow * N + gcol;
                    float g = 0.5f * v * (1.0f + erff(v * 0.70710678118f));
                    outb[oidx] = f2bf(g);
                }
            }
        }
    }
}

// ---------------- V (B,S,NH,DH) bf16 -> Vt (B,NH,DH,S) bf16 ----------------
__global__ void vtrans_kernel(const u16* __restrict__ vb, u16* __restrict__ vt)
{
    __shared__ u16 t[64][65];
    const int blk = blockIdx.x;
    const int st = blk & 15, h = (blk >> 4) & 15, b = blk >> 8;
    const int tid = threadIdx.x;
#pragma unroll
    for (int p = 0; p < 16; ++p) {
        int idx = p * 256 + tid;
        int s = idx >> 6, d = idx & 63;
        t[s][d] = vb[(size_t)(b*SEQ + st*64 + s) * H_DIM + h*DH + d];
    }
    __syncthreads();
#pragma unroll
    for (int p = 0; p < 16; ++p) {
        int idx = p * 256 + tid;
        int d = idx >> 6, s = idx & 63;
        vt[(size_t)((b*NH + h)*DH + d) * SEQ + st*64 + s] = t[s][d];
    }
}

// ---------------- flash attention: Br=64 (4 waves x 16 rows), Bc=64 ----------------
// Per-wave P tile in LDS; NO block barriers (waves fully independent).
__global__ __launch_bounds__(256, 4) void attn_kernel(
    const u16* __restrict__ qb, const u16* __restrict__ kb,
    const u16* __restrict__ vt, const float* __restrict__ mask,
    u16* __restrict__ ctx)
{
    __shared__ u16 plds[4][16 * 80];   // per-wave P tile, stride 80 (160B rows, 16B aligned)
    const int blk = blockIdx.x;
    const int qt = blk & 15, h = (blk >> 4) & 15, b = blk >> 8;
    const int tid = threadIdx.x, w = tid >> 6, lane = tid & 63, q4 = lane >> 4, l16 = lane & 15;

    const u16* qrow = qb + ((size_t)(b*SEQ + qt*64 + w*16 + l16) * H_DIM + h*DH);
    bf16x8_t qf0 = *(const bf16x8_t*)(qrow + q4*8);
    bf16x8_t qf1 = *(const bf16x8_t*)(qrow + 32 + q4*8);

    f32x4_t o[4];
#pragma unroll
    for (int dt = 0; dt < 4; ++dt) o[dt] = (f32x4_t){0.f,0.f,0.f,0.f};
    float mi[4] = {-1e30f,-1e30f,-1e30f,-1e30f};
    float li[4] = {0.f,0.f,0.f,0.f};
    u16* pw = &plds[w][0];

    for (int j = 0; j < 16; ++j) {
        const int kbase = j * 64;
        f32x4_t sc[4];
#pragma unroll
        for (int nt = 0; nt < 4; ++nt) {
            const int kr = kbase + nt*16 + l16;
            const u16* krow = kb + ((size_t)(b*SEQ + kr) * H_DIM + h*DH);
            bf16x8_t kf0 = *(const bf16x8_t*)(krow + q4*8);
            bf16x8_t kf1 = *(const bf16x8_t*)(krow + 32 + q4*8);
            f32x4_t s = (f32x4_t){0.f,0.f,0.f,0.f};
            s = __builtin_amdgcn_mfma_f32_16x16x32_bf16(qf0, kf0, s, 0, 0, 0);
            s = __builtin_amdgcn_mfma_f32_16x16x32_bf16(qf1, kf1, s, 0, 0, 0);
            const float mv = mask[b*SEQ + kr];
            s[0] += mv; s[1] += mv; s[2] += mv; s[3] += mv;
            sc[nt] = s;
        }
        float rm[4], al[4], rs[4];
#pragma unroll
        for (int r = 0; r < 4; ++r)
            rm[r] = fmaxf(fmaxf(sc[0][r], sc[1][r]), fmaxf(sc[2][r], sc[3][r]));
#pragma unroll
        for (int d = 1; d < 16; d <<= 1)
#pragma unroll
            for (int r = 0; r < 4; ++r) rm[r] = fmaxf(rm[r], __shfl_xor(rm[r], d));
#pragma unroll
        for (int r = 0; r < 4; ++r) {
            float nm = fmaxf(mi[r], rm[r]);
            al[r] = __expf(mi[r] - nm);
            mi[r] = nm; rs[r] = 0.f;
        }
#pragma unroll
        for (int nt = 0; nt < 4; ++nt)
#pragma unroll
            for (int r = 0; r < 4; ++r) {
                float p = __expf(sc[nt][r] - mi[r]);
                sc[nt][r] = p; rs[r] += p;
            }
#pragma unroll
        for (int d = 1; d < 16; d <<= 1)
#pragma unroll
            for (int r = 0; r < 4; ++r) rs[r] += __shfl_xor(rs[r], d);
#pragma unroll
        for (int r = 0; r < 4; ++r) li[r] = li[r] * al[r] + rs[r];
#pragma unroll
        for (int dt = 0; dt < 4; ++dt)
#pragma unroll
            for (int r = 0; r < 4; ++r) o[dt][r] *= al[r];

        // issue V loads early: in flight across the P LDS round-trip
        bf16x8_t vf0[4], vf1[4];
#pragma unroll
        for (int dt = 0; dt < 4; ++dt) {
            const u16* vrow = vt + ((size_t)((b*NH + h)*DH + dt*16 + l16) * SEQ + kbase);
            vf0[dt] = *(const bf16x8_t*)(vrow + q4*8);
            vf1[dt] = *(const bf16x8_t*)(vrow + 32 + q4*8);
        }

        // P (C-layout) -> per-wave LDS -> A-layout frags; wave-local ordering only
#pragma unroll
        for (int nt = 0; nt < 4; ++nt)
#pragma unroll
            for (int r = 0; r < 4; ++r)
                pw[(q4*4 + r) * 80 + nt*16 + l16] = f2bf(sc[nt][r]);
        asm volatile("s_waitcnt lgkmcnt(0)" ::: "memory");
        bf16x8_t pf0 = *(const bf16x8_t*)(pw + l16*80 + q4*8);
        bf16x8_t pf1 = *(const bf16x8_t*)(pw + l16*80 + 32 + q4*8);
#pragma unroll
        for (int dt = 0; dt < 4; ++dt) {
            o[dt] = __builtin_amdgcn_mfma_f32_16x16x32_bf16(pf0, vf0[dt], o[dt], 0, 0, 0);
            o[dt] = __builtin_amdgcn_mfma_f32_16x16x32_bf16(pf1, vf1[dt], o[dt], 0, 0, 0);
        }
        asm volatile("" ::: "memory");
    }
    float inv[4];
#pragma unroll
    for (int r = 0; r < 4; ++r) inv[r] = 1.0f / li[r];
#pragma unroll
    for (int dt = 0; dt < 4; ++dt)
#pragma unroll
        for (int r = 0; r < 4; ++r)
            ctx[(size_t)(b*SEQ + qt*64 + w*16 + q4*4 + r) * H_DIM + h*DH + dt*16 + l16]
                = f2bf(o[dt][r] * inv[r]);
}

// ---------------- RMSNorm row kernel: outf = v*rsqrt(mean(v^2)+eps)*g (+ bf16 copy) ----------------
__global__ void rms_kernel(const float* __restrict__ in, const float* __restrict__ g,
                           float* __restrict__ outf, u16* __restrict__ outb)
{
    int row  = blockIdx.x * 4 + (threadIdx.x >> 6);
    int lane = threadIdx.x & 63;
    const f32x4_t* ip = (const f32x4_t*)(in + (size_t)row * H_DIM);
    f32x4_t v[4];
    float ss = 0.f;
#pragma unroll
    for (int k = 0; k < 4; ++k) {
        v[k] = ip[k * 64 + lane];
#pragma unroll
        for (int e = 0; e < 4; ++e) ss += v[k][e] * v[k][e];
    }
#pragma unroll
    for (int m = 32; m; m >>= 1) ss += __shfl_xor(ss, m);
    float sc = rsqrtf(ss * (1.0f / 1024.0f) + 1e-6f);
#pragma unroll
    for (int k = 0; k < 4; ++k) {
        f32x4_t gv = ((const f32x4_t*)g)[k * 64 + lane];
        f32x4_t ov;
        u16x4_t ob;
#pragma unroll
        for (int e = 0; e < 4; ++e) { ov[e] = v[k][e] * sc * gv[e]; ob[e] = f2bf(ov[e]); }
        if (outf) ((f32x4_t*)(outf + (size_t)row * H_DIM))[k * 64 + lane] = ov;
        if (outb) ((u16x4_t*)(outb + (size_t)row * H_DIM))[k * 64 + lane] = ob;
    }
}

extern "C" void kernel_launch(void* const* d_in, const int* in_sizes, int n_in,
                              void* d_out, int out_size, void* d_ws, size_t ws_size,
                              hipStream_t stream)
{
    const float* x   = (const float*)d_in[0];
    const float* y   = (const float*)d_in[1];
    const float* mask= (const float*)d_in[2];
    const float* Wq  = (const float*)d_in[3];
    const float* bq  = (const float*)d_in[4];
    const float* Wk  = (const float*)d_in[5];
    const float* bk  = (const float*)d_in[6];
    const float* Wv  = (const float*)d_in[7];
    const float* bv  = (const float*)d_in[8];
    const float* Wo  = (const float*)d_in[9];
    const float* bo  = (const float*)d_in[10];
    const float* g1  = (const float*)d_in[11];
    const float* Wi  = (const float*)d_in[12];
    const float* bi  = (const float*)d_in[13];
    const float* Wo2 = (const float*)d_in[14];
    const float* bo2 = (const float*)d_in[15];
    const float* g2  = (const float*)d_in[16];
    const int*   tp  = (const int*)d_in[17];
    float* out = (float*)d_out;

    char* ws = (char*)d_ws;
    const size_t MB = 1024 * 1024;
    float* c1    = (float*)(ws);
    float* c2    = (float*)(ws + 16 * 1024);
    float* bkv   = (float*)(ws + 32 * 1024);   // packed bk||bv (2048 f32)
    u16* xs_b    = (u16*)(ws + 1 * MB);    // 8MB; reused as ctx_b after QKV
    u16* ys_b    = (u16*)(ws + 9 * MB);    // 8MB; reused as att_b after V GEMM
    u16* wq_t    = (u16*)(ws + 17 * MB);
    u16* wk_t    = (u16*)(ws + 19 * MB);   // wk_t and wv_t contiguous: fused KV weight
    u16* wv_t    = (u16*)(ws + 21 * MB);
    u16* wo_t    = (u16*)(ws + 23 * MB);
    u16* wi_t    = (u16*)(ws + 25 * MB);   // 8MB
    u16* wo2_t   = (u16*)(ws + 33 * MB);   // 8MB
    u16* qb      = (u16*)(ws + 41 * MB);   // 8MB, reused as inter_b after attention
    u16* kb      = (u16*)(ws + 49 * MB);   // 8MB, kb/vb contiguous: fused KV output
    u16* vb      = (u16*)(ws + 57 * MB);   // 8MB
    u16* vtb     = (u16*)(ws + 65 * MB);   // 8MB
    u16* inter_b = qb;
    float* attpre= (float*)(ws + 73 * MB); // 16MB; reused as ffn2 out
    float* attf  = (float*)(ws + 89 * MB); // 16MB
    (void)ws_size; (void)in_sizes; (void)n_in; (void)out_size; (void)wv_t; (void)vb;

    routing_kernel<<<1024, 256, 0, stream>>>(x, y, tp, c1, c2);
    scale_cast_kernel<<<4096, 256, 0, stream>>>(x, y, c1, c2, xs_b, ys_b);
    pack2_kernel<<<8, 256, 0, stream>>>(bk, bv, bkv);
    wcast_kernel<<<1024, 256, 0, stream>>>(Wq, wq_t, 1024, 1024);
    wcast_kernel<<<1024, 256, 0, stream>>>(Wk, wk_t, 1024, 1024);
    wcast_kernel<<<1024, 256, 0, stream>>>(Wv, wv_t, 1024, 1024);
    wcast_kernel<<<1024, 256, 0, stream>>>(Wo, wo_t, 1024, 1024);
    wcast_kernel<<<4096, 256, 0, stream>>>(Wi, wi_t, 1024, 4096);
    wcast_kernel<<<4096, 256, 0, stream>>>(Wo2, wo2_t, 4096, 1024);

    // Q projection (1/sqrt(DH)=0.125 folded), N=1024, BN=64 -> 512 blocks
    gemm_bt<64><<<512, 256, 0, stream>>>(xs_b, wq_t, 1024, 1024, bq, 0.125f, 0, qb, nullptr, nullptr, nullptr);
    // Fused K+V projection: Bt = [wk_t;wv_t] (2048x1024), out split to kb/vb -> 512 blocks
    gemm_bt<128><<<512, 256, 0, stream>>>(ys_b, wk_t, 2048, 1024, bkv, 1.0f, 0, kb, nullptr, nullptr, nullptr);
    vtrans_kernel<<<1024, 256, 0, stream>>>(vb, vtb);
    attn_kernel<<<1024, 256, 0, stream>>>(qb, kb, vtb, mask, xs_b /*ctx*/);
    // Wo projection + bias + xs residual (xs = c1*x recomputed in f32)
    gemm_bt<64><<<512, 256, 0, stream>>>(xs_b, wo_t, 1024, 1024, bo, 1.0f, 1, nullptr, attpre, c1, x);
    rms_kernel<<<1024, 256, 0, stream>>>(attpre, g1, attf, ys_b /*att_b*/);
    // FFN up + exact GELU, N=4096 -> 1024 blocks
    gemm_bt<128><<<1024, 256, 0, stream>>>(ys_b, wi_t, 4096, 1024, bi, 1.0f, 2, inter_b, nullptr, nullptr, nullptr);
    // FFN down + bias + att residual, N=1024, K=4096, BN=64 -> 512 blocks
    gemm_bt<64><<<512, 256, 0, stream>>>(inter_b, wo2_t, 1024, 4096, bo2, 1.0f, 1, nullptr, attpre, nullptr, attf);
    rms_kernel<<<1024, 256, 0, stream>>>(attpre, g2, out, nullptr);
}

// Round 4
// 538.068 us; speedup vs baseline: 1.2433x; 1.0596x over previous
//
#include <hip/hip_runtime.h>

typedef unsigned short u16;
typedef __attribute__((ext_vector_type(8))) short bf16x8_t;   // 8 bf16 (4 VGPRs)
typedef __attribute__((ext_vector_type(4))) float f32x4_t;
typedef __attribute__((ext_vector_type(4))) unsigned short u16x4_t;

#define H_DIM 1024
#define NH 16
#define DH 64
#define I_DIM 4096
#define BATCH 4
#define SEQ 1024
#define M_ROWS 4096   /* BATCH*SEQ */

__device__ __forceinline__ u16 f2bf(float f) {
    unsigned int u = __builtin_bit_cast(unsigned int, f);
    u += 0x7fffu + ((u >> 16) & 1u);
    return (u16)(u >> 16);
}

__device__ __forceinline__ void gld16(const void* g, void* l) {
    __builtin_amdgcn_global_load_lds(
        (const __attribute__((address_space(1))) unsigned int*)g,
        (__attribute__((address_space(3))) unsigned int*)l,
        16, 0, 0);
}

// ------- fused routing + scale/cast: Gram dots -> t-loop -> xs=bf16(c1*x), ys=bf16(c2*y) -------
__global__ void route_scale_kernel(const float* __restrict__ x, const float* __restrict__ y,
                                   const int* __restrict__ tptr,
                                   float* __restrict__ c1o, float* __restrict__ c2o,
                                   u16* __restrict__ xs, u16* __restrict__ ys)
{
    int tok  = blockIdx.x * 4 + (threadIdx.x >> 6);
    int lane = threadIdx.x & 63;
    const f32x4_t* xp = (const f32x4_t*)(x + (size_t)tok * H_DIM);
    const f32x4_t* yp = (const f32x4_t*)(y + (size_t)tok * H_DIM);
    f32x4_t xv[4], yv[4];
    float xx = 0.f, xy = 0.f, yy = 0.f;
#pragma unroll
    for (int k = 0; k < 4; ++k) {
        xv[k] = xp[k * 64 + lane]; yv[k] = yp[k * 64 + lane];
#pragma unroll
        for (int e = 0; e < 4; ++e) {
            xx += xv[k][e]*xv[k][e]; xy += xv[k][e]*yv[k][e]; yy += yv[k][e]*yv[k][e];
        }
    }
#pragma unroll
    for (int m = 32; m; m >>= 1) {
        xx += __shfl_xor(xx, m); xy += __shfl_xor(xy, m); yy += __shfl_xor(yy, m);
    }
    int T = tptr[0];
    float c1 = 0.5f, c2 = 0.5f, b1 = 0.f, b2 = 0.f;
    for (int i = 0; i < T; ++i) {
        if (i > 0) {
            float mx = fmaxf(b1, b2);
            float e1 = __expf(b1 - mx), e2 = __expf(b2 - mx);
            float inv = 1.0f / (e1 + e2);
            c1 = e1 * inv; c2 = e2 * inv;
        }
        float vv = c1*c1*xx + 2.0f*c1*c2*xy + c2*c2*yy;
        float n  = sqrtf(vv);
        float s  = n / (1.0f + vv);            // n/(1+n^2), n^2 == vv
        float d1 = s * (c1*xx + c2*xy);
        float d2 = s * (c1*xy + c2*yy);
        b1 += d1; b2 += d2;
    }
    if (lane == 0) { c1o[tok] = c1; c2o[tok] = c2; }
#pragma unroll
    for (int k = 0; k < 4; ++k) {
        u16x4_t xo, yo;
#pragma unroll
        for (int e = 0; e < 4; ++e) { xo[e] = f2bf(xv[k][e]*c1); yo[e] = f2bf(yv[k][e]*c2); }
        ((u16x4_t*)(xs + (size_t)tok * H_DIM))[k * 64 + lane] = xo;
        ((u16x4_t*)(ys + (size_t)tok * H_DIM))[k * 64 + lane] = yo;
    }
}

// ---------------- pack two 1024-bias vectors into one 2048 buffer ----------------
__global__ void pack2_kernel(const float* __restrict__ a, const float* __restrict__ b,
                             float* __restrict__ o)
{
    int i = blockIdx.x * 256 + threadIdx.x;   // 0..2047
    o[i] = (i < 1024) ? a[i] : b[i - 1024];
}

// ---------------- W (Kw x Nw) f32 -> W^T (Nw x Kw) bf16 ----------------
__device__ __forceinline__ void wcast_body(const float* __restrict__ W, u16* __restrict__ Wt,
                                           int Kw, int Nw, int blk, int tid, float* t /*32x33*/)
{
    int nbj = Nw >> 5;
    int bi = blk / nbj, bj = blk % nbj;
#pragma unroll
    for (int p = 0; p < 4; ++p) {
        int idx = p * 256 + tid;
        int r = idx >> 5, c = idx & 31;
        t[r * 33 + c] = W[(size_t)(bi*32 + r) * Nw + bj*32 + c];
    }
    __syncthreads();
#pragma unroll
    for (int p = 0; p < 4; ++p) {
        int idx = p * 256 + tid;
        int r = idx >> 5, c = idx & 31;
        Wt[(size_t)(bj*32 + r) * Kw + bi*32 + c] = f2bf(t[c * 33 + r]);
    }
}

__global__ void wcast_kernel(const float* __restrict__ W, u16* __restrict__ Wt, int Kw, int Nw)
{
    __shared__ float t[32 * 33];
    wcast_body(W, Wt, Kw, Nw, blockIdx.x, threadIdx.x, t);
}

// four H_DIMxH_DIM weights in one launch (4096 blocks)
__global__ void wcast4_kernel(const float* __restrict__ W0, const float* __restrict__ W1,
                              const float* __restrict__ W2, const float* __restrict__ W3,
                              u16* __restrict__ T0, u16* __restrict__ T1,
                              u16* __restrict__ T2, u16* __restrict__ T3)
{
    __shared__ float t[32 * 33];
    int which = blockIdx.x >> 10, blk = blockIdx.x & 1023;
    const float* W = (which == 0) ? W0 : (which == 1) ? W1 : (which == 2) ? W2 : W3;
    u16* Wt = (which == 0) ? T0 : (which == 1) ? T1 : (which == 2) ? T2 : T3;
    wcast_body(W, Wt, 1024, 1024, blk, threadIdx.x, t);
}

// ---------------- GEMM: C = A(M,K) @ Bt(N,K)^T, bf16 in, f32 accum ----------------
// epi 0: outb[(gcol>>10)*M*H + grow*H + (gcol&1023)] = bf16((acc+bias)*(gcol<1024?scale:1))
//        (QKV-style split output; for N=1024 it degenerates to a plain store)
// epi 1: outf = acc + bias + (rscale?rscale[row]:1)*resm[row,col]
// epi 2: outb = bf16(gelu_exact(acc+bias))
#define BK 64

template<int TBN>
__global__ __launch_bounds__(256, (TBN == 128) ? 3 : 4) void gemm_bt(
    const u16* __restrict__ A, const u16* __restrict__ Bt, int N, int K,
    const float* __restrict__ bias, float scale, int epi,
    u16* __restrict__ outb, float* __restrict__ outf,
    const float* __restrict__ rscale, const float* __restrict__ resm)
{
    constexpr int TBM = 128;
    constexpr int MT = (TBN == 128) ? 4 : 2;
    constexpr int NT = 4;
    __shared__ u16 As[TBM * BK];   // 16KB
    __shared__ u16 Bs[TBN * BK];   // 16KB or 8KB
    const int ntN = N / TBN;
    const int tm = blockIdx.x / ntN, tn = blockIdx.x % ntN;
    const int tid = threadIdx.x;
    const int w = tid >> 6, lane = tid & 63, q4 = lane >> 4, l16 = lane & 15;
    const int wm = (TBN == 128) ? (w >> 1) * 64 : w * 32;
    const int wn = (TBN == 128) ? (w & 1) * 64 : 0;

    // staging map: chunk c covers rows c*32..c*32+31; thread -> row tid>>3, col (tid&7)*8
    const int srow = tid >> 3;
    const int scol = (tid & 7) * 8;
    const u16* ga = A  + (size_t)(tm * TBM + srow) * K + scol;
    const u16* gb = Bt + (size_t)(tn * TBN + srow) * K + scol;

    f32x4_t acc[MT][NT];
#pragma unroll
    for (int mt = 0; mt < MT; ++mt)
#pragma unroll
        for (int nt = 0; nt < NT; ++nt) acc[mt][nt] = (f32x4_t){0.f,0.f,0.f,0.f};

    for (int k0 = 0; k0 < K; k0 += BK) {
        __syncthreads();
#pragma unroll
        for (int c = 0; c < 4; ++c)
            gld16(ga + (size_t)c * 32 * K + k0, &As[c * 2048 + w * 512]);
#pragma unroll
        for (int c = 0; c < TBN/32; ++c)
            gld16(gb + (size_t)c * 32 * K + k0, &Bs[c * 2048 + w * 512]);
        __syncthreads();
#pragma unroll
        for (int kc = 0; kc < 2; ++kc) {
            bf16x8_t af[MT], bfr[NT];
#pragma unroll
            for (int mt = 0; mt < MT; ++mt)
                af[mt] = *(const bf16x8_t*)&As[(wm + mt*16 + l16) * BK + kc*32 + q4*8];
#pragma unroll
            for (int nt = 0; nt < NT; ++nt)
                bfr[nt] = *(const bf16x8_t*)&Bs[(wn + nt*16 + l16) * BK + kc*32 + q4*8];
#pragma unroll
            for (int mt = 0; mt < MT; ++mt)
#pragma unroll
                for (int nt = 0; nt < NT; ++nt)
                    acc[mt][nt] = __builtin_amdgcn_mfma_f32_16x16x32_bf16(af[mt], bfr[nt], acc[mt][nt], 0, 0, 0);
        }
    }

#pragma unroll
    for (int mt = 0; mt < MT; ++mt) {
#pragma unroll
        for (int nt = 0; nt < NT; ++nt) {
            const int gcol = tn * TBN + wn + nt*16 + l16;
            const float bv = bias[gcol];
#pragma unroll
            for (int r = 0; r < 4; ++r) {
                const int grow = tm * TBM + wm + mt*16 + q4*4 + r;
                float v = acc[mt][nt][r] + bv;
                if (epi == 0) {
                    float sc2 = (gcol < 1024) ? scale : 1.0f;
                    size_t o = (size_t)(gcol >> 10) * ((size_t)M_ROWS * H_DIM)
                             + (size_t)grow * H_DIM + (gcol & 1023);
                    outb[o] = f2bf(v * sc2);
                } else if (epi == 1) {
                    const size_t oidx = (size_t)grow * N + gcol;
                    float rs = rscale ? rscale[grow] : 1.0f;
                    outf[oidx] = v + rs * resm[oidx];
                } else {
                    const size_t oidx = (size_t)grow * N + gcol;
                    float g = 0.5f * v * (1.0f + erff(v * 0.70710678118f));
                    outb[oidx] = f2bf(g);
                }
            }
        }
    }
}

// ---------------- V (B,S,NH,DH) bf16 -> Vt (B,NH,DH,S) bf16 ----------------
__global__ void vtrans_kernel(const u16* __restrict__ vb, u16* __restrict__ vt)
{
    __shared__ u16 t[64][65];
    const int blk = blockIdx.x;
    const int st = blk & 15, h = (blk >> 4) & 15, b = blk >> 8;
    const int tid = threadIdx.x;
#pragma unroll
    for (int p = 0; p < 16; ++p) {
        int idx = p * 256 + tid;
        int s = idx >> 6, d = idx & 63;
        t[s][d] = vb[(size_t)(b*SEQ + st*64 + s) * H_DIM + h*DH + d];
    }
    __syncthreads();
#pragma unroll
    for (int p = 0; p < 16; ++p) {
        int idx = p * 256 + tid;
        int d = idx >> 6, s = idx & 63;
        vt[(size_t)((b*NH + h)*DH + d) * SEQ + st*64 + s] = t[s][d];
    }
}

// ---------------- flash attention, S^T formulation ----------------
// Each wave: 16 q-rows (q = lane&15). S^T = K*Q^T via swapped MFMA operands ->
// softmax state is per-thread scalar; O^T = V^T*P^T. K double-buffered in regs.
__global__ __launch_bounds__(256, 3) void attn_kernel(
    const u16* __restrict__ qb, const u16* __restrict__ kb,
    const u16* __restrict__ vt, const float* __restrict__ mask,
    u16* __restrict__ ctx)
{
    __shared__ u16 plds[4][16 * 72];   // per-wave P^T tile, stride 72 u16 (144B, 16B-aligned)
    const int blk = blockIdx.x;
    const int qt = blk & 15, h = (blk >> 4) & 15, b = blk >> 8;
    const int tid = threadIdx.x, w = tid >> 6, lane = tid & 63, q4 = lane >> 4, l16 = lane & 15;

    const u16* qrow = qb + ((size_t)(b*SEQ + qt*64 + w*16 + l16) * H_DIM + h*DH);
    bf16x8_t qf0 = *(const bf16x8_t*)(qrow + q4*8);
    bf16x8_t qf1 = *(const bf16x8_t*)(qrow + 32 + q4*8);

    const u16* kbp   = kb + ((size_t)(b*SEQ) * H_DIM + h*DH);
    const u16* vbase = vt + ((size_t)((b*NH + h)*DH) * SEQ);
    const float* mrow = mask + b*SEQ;

    f32x4_t o[4];
#pragma unroll
    for (int dt = 0; dt < 4; ++dt) o[dt] = (f32x4_t){0.f,0.f,0.f,0.f};
    float mi = -1e30f, li = 0.f;
    u16* pw = &plds[w][0];

    // K current/next register double-buffer (thread covers key rows nt*16+l16)
    bf16x8_t kc0[4], kc1[4], kn0[4], kn1[4];
#pragma unroll
    for (int nt = 0; nt < 4; ++nt) {
        const u16* kr = kbp + (size_t)(nt*16 + l16) * H_DIM;
        kc0[nt] = *(const bf16x8_t*)(kr + q4*8);
        kc1[nt] = *(const bf16x8_t*)(kr + 32 + q4*8);
    }

    for (int j = 0; j < 16; ++j) {
        const int kb0 = j * 64;
        // V loads for this tile: in flight across QK + softmax
        bf16x8_t vf0[4], vf1[4];
#pragma unroll
        for (int dt = 0; dt < 4; ++dt) {
            const u16* vrow = vbase + (size_t)(dt*16 + l16) * SEQ + kb0;
            vf0[dt] = *(const bf16x8_t*)(vrow + q4*8);
            vf1[dt] = *(const bf16x8_t*)(vrow + 32 + q4*8);
        }
        // prefetch next K tile (lands during softmax/PV)
        if (j < 15) {
#pragma unroll
            for (int nt = 0; nt < 4; ++nt) {
                const u16* kr = kbp + (size_t)(kb0 + 64 + nt*16 + l16) * H_DIM;
                kn0[nt] = *(const bf16x8_t*)(kr + q4*8);
                kn1[nt] = *(const bf16x8_t*)(kr + 32 + q4*8);
            }
        }
        // S^T tile: row=key=q4*4+r (block nt), col=q=l16
        f32x4_t sc[4];
#pragma unroll
        for (int nt = 0; nt < 4; ++nt) {
            f32x4_t s = (f32x4_t){0.f,0.f,0.f,0.f};
            s = __builtin_amdgcn_mfma_f32_16x16x32_bf16(kc0[nt], qf0, s, 0, 0, 0);
            s = __builtin_amdgcn_mfma_f32_16x16x32_bf16(kc1[nt], qf1, s, 0, 0, 0);
            f32x4_t mv = *(const f32x4_t*)&mrow[kb0 + nt*16 + q4*4];
#pragma unroll
            for (int r = 0; r < 4; ++r) s[r] += mv[r];
            sc[nt] = s;
        }
        // per-thread softmax over 16 keys + 2-shfl cross-q4 reduction
        float tmax = sc[0][0];
#pragma unroll
        for (int nt = 0; nt < 4; ++nt)
#pragma unroll
            for (int r = 0; r < 4; ++r) tmax = fmaxf(tmax, sc[nt][r]);
        tmax = fmaxf(tmax, __shfl_xor(tmax, 16));
        tmax = fmaxf(tmax, __shfl_xor(tmax, 32));
        float nm = fmaxf(mi, tmax);
        float al = __expf(mi - nm);
        mi = nm;
        float rs = 0.f;
#pragma unroll
        for (int nt = 0; nt < 4; ++nt)
#pragma unroll
            for (int r = 0; r < 4; ++r) {
                float p = __expf(sc[nt][r] - nm);
                sc[nt][r] = p; rs += p;
            }
        rs += __shfl_xor(rs, 16);
        rs += __shfl_xor(rs, 32);
        li = li * al + rs;
#pragma unroll
        for (int dt = 0; dt < 4; ++dt)
#pragma unroll
            for (int r = 0; r < 4; ++r) o[dt][r] *= al;

        // P^T -> per-wave LDS (row q=l16), 4x b64 writes, wave-local ordering only
#pragma unroll
        for (int nt = 0; nt < 4; ++nt) {
            u16x4_t pb;
#pragma unroll
            for (int r = 0; r < 4; ++r) pb[r] = f2bf(sc[nt][r]);
            *(u16x4_t*)&pw[l16*72 + nt*16 + q4*4] = pb;
        }
        asm volatile("s_waitcnt lgkmcnt(0)" ::: "memory");
        bf16x8_t pf0 = *(const bf16x8_t*)&pw[l16*72 + q4*8];
        bf16x8_t pf1 = *(const bf16x8_t*)&pw[l16*72 + 32 + q4*8];
#pragma unroll
        for (int dt = 0; dt < 4; ++dt) {
            o[dt] = __builtin_amdgcn_mfma_f32_16x16x32_bf16(vf0[dt], pf0, o[dt], 0, 0, 0);
            o[dt] = __builtin_amdgcn_mfma_f32_16x16x32_bf16(vf1[dt], pf1, o[dt], 0, 0, 0);
        }
        asm volatile("" ::: "memory");
#pragma unroll
        for (int nt = 0; nt < 4; ++nt) { kc0[nt] = kn0[nt]; kc1[nt] = kn1[nt]; }
    }
    const float inv = 1.0f / li;
    const size_t tokbase = (size_t)(b*SEQ + qt*64 + w*16 + l16) * H_DIM + h*DH;
#pragma unroll
    for (int dt = 0; dt < 4; ++dt) {
        u16x4_t ob;
#pragma unroll
        for (int r = 0; r < 4; ++r) ob[r] = f2bf(o[dt][r] * inv);
        *(u16x4_t*)&ctx[tokbase + dt*16 + q4*4] = ob;
    }
}

// ---------------- RMSNorm row kernel: outf = v*rsqrt(mean(v^2)+eps)*g (+ bf16 copy) ----------------
__global__ void rms_kernel(const float* __restrict__ in, const float* __restrict__ g,
                           float* __restrict__ outf, u16* __restrict__ outb)
{
    int row  = blockIdx.x * 4 + (threadIdx.x >> 6);
    int lane = threadIdx.x & 63;
    const f32x4_t* ip = (const f32x4_t*)(in + (size_t)row * H_DIM);
    f32x4_t v[4];
    float ss = 0.f;
#pragma unroll
    for (int k = 0; k < 4; ++k) {
        v[k] = ip[k * 64 + lane];
#pragma unroll
        for (int e = 0; e < 4; ++e) ss += v[k][e] * v[k][e];
    }
#pragma unroll
    for (int m = 32; m; m >>= 1) ss += __shfl_xor(ss, m);
    float sc = rsqrtf(ss * (1.0f / 1024.0f) + 1e-6f);
#pragma unroll
    for (int k = 0; k < 4; ++k) {
        f32x4_t gv = ((const f32x4_t*)g)[k * 64 + lane];
        f32x4_t ov;
        u16x4_t ob;
#pragma unroll
        for (int e = 0; e < 4; ++e) { ov[e] = v[k][e] * sc * gv[e]; ob[e] = f2bf(ov[e]); }
        if (outf) ((f32x4_t*)(outf + (size_t)row * H_DIM))[k * 64 + lane] = ov;
        if (outb) ((u16x4_t*)(outb + (size_t)row * H_DIM))[k * 64 + lane] = ob;
    }
}

extern "C" void kernel_launch(void* const* d_in, const int* in_sizes, int n_in,
                              void* d_out, int out_size, void* d_ws, size_t ws_size,
                              hipStream_t stream)
{
    const float* x   = (const float*)d_in[0];
    const float* y   = (const float*)d_in[1];
    const float* mask= (const float*)d_in[2];
    const float* Wq  = (const float*)d_in[3];
    const float* bq  = (const float*)d_in[4];
    const float* Wk  = (const float*)d_in[5];
    const float* bk  = (const float*)d_in[6];
    const float* Wv  = (const float*)d_in[7];
    const float* bv  = (const float*)d_in[8];
    const float* Wo  = (const float*)d_in[9];
    const float* bo  = (const float*)d_in[10];
    const float* g1  = (const float*)d_in[11];
    const float* Wi  = (const float*)d_in[12];
    const float* bi  = (const float*)d_in[13];
    const float* Wo2 = (const float*)d_in[14];
    const float* bo2 = (const float*)d_in[15];
    const float* g2  = (const float*)d_in[16];
    const int*   tp  = (const int*)d_in[17];
    float* out = (float*)d_out;

    char* ws = (char*)d_ws;
    const size_t MB = 1024 * 1024;
    float* c1    = (float*)(ws);
    float* c2    = (float*)(ws + 16 * 1024);
    float* bkv   = (float*)(ws + 32 * 1024);   // packed bk||bv (2048 f32)
    u16* xs_b    = (u16*)(ws + 1 * MB);    // 8MB; reused as ctx_b after QKV
    u16* ys_b    = (u16*)(ws + 9 * MB);    // 8MB; reused as att_b after V GEMM
    u16* wq_t    = (u16*)(ws + 17 * MB);
    u16* wk_t    = (u16*)(ws + 19 * MB);   // wk_t and wv_t contiguous: fused KV weight
    u16* wv_t    = (u16*)(ws + 21 * MB);
    u16* wo_t    = (u16*)(ws + 23 * MB);
    u16* wi_t    = (u16*)(ws + 25 * MB);   // 8MB
    u16* wo2_t   = (u16*)(ws + 33 * MB);   // 8MB
    u16* qb      = (u16*)(ws + 41 * MB);   // 8MB, reused as inter_b after attention
    u16* kb      = (u16*)(ws + 49 * MB);   // 8MB, kb/vb contiguous: fused KV output
    u16* vb      = (u16*)(ws + 57 * MB);   // 8MB
    u16* vtb     = (u16*)(ws + 65 * MB);   // 8MB
    u16* inter_b = qb;
    float* attpre= (float*)(ws + 73 * MB); // 16MB; reused as ffn2 out
    float* attf  = (float*)(ws + 89 * MB); // 16MB
    (void)ws_size; (void)in_sizes; (void)n_in; (void)out_size; (void)wv_t; (void)vb;

    route_scale_kernel<<<1024, 256, 0, stream>>>(x, y, tp, c1, c2, xs_b, ys_b);
    pack2_kernel<<<8, 256, 0, stream>>>(bk, bv, bkv);
    wcast4_kernel<<<4096, 256, 0, stream>>>(Wq, Wk, Wv, Wo, wq_t, wk_t, wv_t, wo_t);
    wcast_kernel<<<4096, 256, 0, stream>>>(Wi, wi_t, 1024, 4096);
    wcast_kernel<<<4096, 256, 0, stream>>>(Wo2, wo2_t, 4096, 1024);

    // Q projection (1/sqrt(DH)=0.125 folded), N=1024, BN=64 -> 512 blocks
    gemm_bt<64><<<512, 256, 0, stream>>>(xs_b, wq_t, 1024, 1024, bq, 0.125f, 0, qb, nullptr, nullptr, nullptr);
    // Fused K+V projection: Bt = [wk_t;wv_t] (2048x1024), out split to kb/vb -> 512 blocks
    gemm_bt<128><<<512, 256, 0, stream>>>(ys_b, wk_t, 2048, 1024, bkv, 1.0f, 0, kb, nullptr, nullptr, nullptr);
    vtrans_kernel<<<1024, 256, 0, stream>>>(vb, vtb);
    attn_kernel<<<1024, 256, 0, stream>>>(qb, kb, vtb, mask, xs_b /*ctx*/);
    // Wo projection + bias + xs residual (xs = c1*x recomputed in f32)
    gemm_bt<64><<<512, 256, 0, stream>>>(xs_b, wo_t, 1024, 1024, bo, 1.0f, 1, nullptr, attpre, c1, x);
    rms_kernel<<<1024, 256, 0, stream>>>(attpre, g1, attf, ys_b /*att_b*/);
    // FFN up + exact GELU, N=4096 -> 1024 blocks
    gemm_bt<128><<<1024, 256, 0, stream>>>(ys_b, wi_t, 4096, 1024, bi, 1.0f, 2, inter_b, nullptr, nullptr, nullptr);
    // FFN down + bias + att residual, N=1024, K=4096, BN=64 -> 512 blocks
    gemm_bt<64><<<512, 256, 0, stream>>>(inter_b, wo2_t, 1024, 4096, bo2, 1.0f, 1, nullptr, attpre, nullptr, attf);
    rms_kernel<<<1024, 256, 0, stream>>>(attpre, g2, out, nullptr);
}

// Round 5
// 472.600 us; speedup vs baseline: 1.4155x; 1.1385x over previous
//
#include <hip/hip_runtime.h>

typedef unsigned short u16;
typedef __attribute__((ext_vector_type(8))) short bf16x8_t;   // 8 bf16 (4 VGPRs)
typedef __attribute__((ext_vector_type(4))) float f32x4_t;
typedef __attribute__((ext_vector_type(4))) unsigned short u16x4_t;

#define H_DIM 1024
#define NH 16
#define DH 64
#define I_DIM 4096
#define BATCH 4
#define SEQ 1024
#define M_ROWS 4096   /* BATCH*SEQ */

__device__ __forceinline__ u16 f2bf(float f) {
    unsigned int u = __builtin_bit_cast(unsigned int, f);
    u += 0x7fffu + ((u >> 16) & 1u);
    return (u16)(u >> 16);
}

__device__ __forceinline__ void gld16(const void* g, void* l) {
    __builtin_amdgcn_global_load_lds(
        (const __attribute__((address_space(1))) unsigned int*)g,
        (__attribute__((address_space(3))) unsigned int*)l,
        16, 0, 0);
}

// ------- fused routing + scale/cast: Gram dots -> t-loop -> xs=bf16(c1*x), ys=bf16(c2*y) -------
__global__ void route_scale_kernel(const float* __restrict__ x, const float* __restrict__ y,
                                   const int* __restrict__ tptr,
                                   float* __restrict__ c1o, float* __restrict__ c2o,
                                   u16* __restrict__ xs, u16* __restrict__ ys)
{
    int tok  = blockIdx.x * 4 + (threadIdx.x >> 6);
    int lane = threadIdx.x & 63;
    const f32x4_t* xp = (const f32x4_t*)(x + (size_t)tok * H_DIM);
    const f32x4_t* yp = (const f32x4_t*)(y + (size_t)tok * H_DIM);
    f32x4_t xv[4], yv[4];
    float xx = 0.f, xy = 0.f, yy = 0.f;
#pragma unroll
    for (int k = 0; k < 4; ++k) {
        xv[k] = xp[k * 64 + lane]; yv[k] = yp[k * 64 + lane];
#pragma unroll
        for (int e = 0; e < 4; ++e) {
            xx += xv[k][e]*xv[k][e]; xy += xv[k][e]*yv[k][e]; yy += yv[k][e]*yv[k][e];
        }
    }
#pragma unroll
    for (int m = 32; m; m >>= 1) {
        xx += __shfl_xor(xx, m); xy += __shfl_xor(xy, m); yy += __shfl_xor(yy, m);
    }
    int T = tptr[0];
    float c1 = 0.5f, c2 = 0.5f, b1 = 0.f, b2 = 0.f;
    for (int i = 0; i < T; ++i) {
        if (i > 0) {
            float mx = fmaxf(b1, b2);
            float e1 = __expf(b1 - mx), e2 = __expf(b2 - mx);
            float inv = 1.0f / (e1 + e2);
            c1 = e1 * inv; c2 = e2 * inv;
        }
        float vv = c1*c1*xx + 2.0f*c1*c2*xy + c2*c2*yy;
        float n  = sqrtf(vv);
        float s  = n / (1.0f + vv);            // n/(1+n^2), n^2 == vv
        float d1 = s * (c1*xx + c2*xy);
        float d2 = s * (c1*xy + c2*yy);
        b1 += d1; b2 += d2;
    }
    if (lane == 0) { c1o[tok] = c1; c2o[tok] = c2; }
#pragma unroll
    for (int k = 0; k < 4; ++k) {
        u16x4_t xo, yo;
#pragma unroll
        for (int e = 0; e < 4; ++e) { xo[e] = f2bf(xv[k][e]*c1); yo[e] = f2bf(yv[k][e]*c2); }
        ((u16x4_t*)(xs + (size_t)tok * H_DIM))[k * 64 + lane] = xo;
        ((u16x4_t*)(ys + (size_t)tok * H_DIM))[k * 64 + lane] = yo;
    }
}

// ---------------- pack two 1024-bias vectors into one 2048 buffer ----------------
__global__ void pack2_kernel(const float* __restrict__ a, const float* __restrict__ b,
                             float* __restrict__ o)
{
    int i = blockIdx.x * 256 + threadIdx.x;   // 0..2047
    o[i] = (i < 1024) ? a[i] : b[i - 1024];
}

// ---------------- W (Kw x Nw) f32 -> W^T (Nw x Kw) bf16 ----------------
__device__ __forceinline__ void wcast_body(const float* __restrict__ W, u16* __restrict__ Wt,
                                           int Kw, int Nw, int blk, int tid, float* t /*32x33*/)
{
    int nbj = Nw >> 5;
    int bi = blk / nbj, bj = blk % nbj;
#pragma unroll
    for (int p = 0; p < 4; ++p) {
        int idx = p * 256 + tid;
        int r = idx >> 5, c = idx & 31;
        t[r * 33 + c] = W[(size_t)(bi*32 + r) * Nw + bj*32 + c];
    }
    __syncthreads();
#pragma unroll
    for (int p = 0; p < 4; ++p) {
        int idx = p * 256 + tid;
        int r = idx >> 5, c = idx & 31;
        Wt[(size_t)(bj*32 + r) * Kw + bi*32 + c] = f2bf(t[c * 33 + r]);
    }
}

__global__ void wcast_kernel(const float* __restrict__ W, u16* __restrict__ Wt, int Kw, int Nw)
{
    __shared__ float t[32 * 33];
    wcast_body(W, Wt, Kw, Nw, blockIdx.x, threadIdx.x, t);
}

// four H_DIMxH_DIM weights in one launch (4096 blocks)
__global__ void wcast4_kernel(const float* __restrict__ W0, const float* __restrict__ W1,
                              const float* __restrict__ W2, const float* __restrict__ W3,
                              u16* __restrict__ T0, u16* __restrict__ T1,
                              u16* __restrict__ T2, u16* __restrict__ T3)
{
    __shared__ float t[32 * 33];
    int which = blockIdx.x >> 10, blk = blockIdx.x & 1023;
    const float* W = (which == 0) ? W0 : (which == 1) ? W1 : (which == 2) ? W2 : W3;
    u16* Wt = (which == 0) ? T0 : (which == 1) ? T1 : (which == 2) ? T2 : T3;
    wcast_body(W, Wt, 1024, 1024, blk, threadIdx.x, t);
}

// ---------------- GEMM: C = A(M,K) @ Bt(N,K)^T, bf16 in, f32 accum ----------------
// epi 0: outb[(gcol>>10)*M*H + grow*H + (gcol&1023)] = bf16((acc+bias)*(gcol<1024?scale:1))
//        (QKV-style split output; for N=1024 it degenerates to a plain store)
// epi 1: outf = acc + bias + (rscale?rscale[row]:1)*resm[row,col]
// epi 2: outb = bf16(gelu_exact(acc+bias))
#define BK 64

template<int TBN>
__global__ __launch_bounds__(256, (TBN == 128) ? 3 : 4) void gemm_bt(
    const u16* __restrict__ A, const u16* __restrict__ Bt, int N, int K,
    const float* __restrict__ bias, float scale, int epi,
    u16* __restrict__ outb, float* __restrict__ outf,
    const float* __restrict__ rscale, const float* __restrict__ resm)
{
    constexpr int TBM = 128;
    constexpr int MT = (TBN == 128) ? 4 : 2;
    constexpr int NT = 4;
    __shared__ u16 As[TBM * BK];   // 16KB
    __shared__ u16 Bs[TBN * BK];   // 16KB or 8KB
    const int ntN = N / TBN;
    const int tm = blockIdx.x / ntN, tn = blockIdx.x % ntN;
    const int tid = threadIdx.x;
    const int w = tid >> 6, lane = tid & 63, q4 = lane >> 4, l16 = lane & 15;
    const int wm = (TBN == 128) ? (w >> 1) * 64 : w * 32;
    const int wn = (TBN == 128) ? (w & 1) * 64 : 0;

    // staging map: chunk c covers rows c*32..c*32+31; thread -> row tid>>3, col (tid&7)*8
    const int srow = tid >> 3;
    const int scol = (tid & 7) * 8;
    const u16* ga = A  + (size_t)(tm * TBM + srow) * K + scol;
    const u16* gb = Bt + (size_t)(tn * TBN + srow) * K + scol;

    f32x4_t acc[MT][NT];
#pragma unroll
    for (int mt = 0; mt < MT; ++mt)
#pragma unroll
        for (int nt = 0; nt < NT; ++nt) acc[mt][nt] = (f32x4_t){0.f,0.f,0.f,0.f};

    for (int k0 = 0; k0 < K; k0 += BK) {
        __syncthreads();
#pragma unroll
        for (int c = 0; c < 4; ++c)
            gld16(ga + (size_t)c * 32 * K + k0, &As[c * 2048 + w * 512]);
#pragma unroll
        for (int c = 0; c < TBN/32; ++c)
            gld16(gb + (size_t)c * 32 * K + k0, &Bs[c * 2048 + w * 512]);
        __syncthreads();
#pragma unroll
        for (int kc = 0; kc < 2; ++kc) {
            bf16x8_t af[MT], bfr[NT];
#pragma unroll
            for (int mt = 0; mt < MT; ++mt)
                af[mt] = *(const bf16x8_t*)&As[(wm + mt*16 + l16) * BK + kc*32 + q4*8];
#pragma unroll
            for (int nt = 0; nt < NT; ++nt)
                bfr[nt] = *(const bf16x8_t*)&Bs[(wn + nt*16 + l16) * BK + kc*32 + q4*8];
#pragma unroll
            for (int mt = 0; mt < MT; ++mt)
#pragma unroll
                for (int nt = 0; nt < NT; ++nt)
                    acc[mt][nt] = __builtin_amdgcn_mfma_f32_16x16x32_bf16(af[mt], bfr[nt], acc[mt][nt], 0, 0, 0);
        }
    }

#pragma unroll
    for (int mt = 0; mt < MT; ++mt) {
#pragma unroll
        for (int nt = 0; nt < NT; ++nt) {
            const int gcol = tn * TBN + wn + nt*16 + l16;
            const float bv = bias[gcol];
#pragma unroll
            for (int r = 0; r < 4; ++r) {
                const int grow = tm * TBM + wm + mt*16 + q4*4 + r;
                float v = acc[mt][nt][r] + bv;
                if (epi == 0) {
                    float sc2 = (gcol < 1024) ? scale : 1.0f;
                    size_t o = (size_t)(gcol >> 10) * ((size_t)M_ROWS * H_DIM)
                             + (size_t)grow * H_DIM + (gcol & 1023);
                    outb[o] = f2bf(v * sc2);
                } else if (epi == 1) {
                    const size_t oidx = (size_t)grow * N + gcol;
                    float rs = rscale ? rscale[grow] : 1.0f;
                    outf[oidx] = v + rs * resm[oidx];
                } else {
                    const size_t oidx = (size_t)grow * N + gcol;
                    float g = 0.5f * v * (1.0f + erff(v * 0.70710678118f));
                    outb[oidx] = f2bf(g);
                }
            }
        }
    }
}

// ---------------- V (B,S,NH,DH) bf16 -> Vt (B,NH,DH,S) bf16 ----------------
__global__ void vtrans_kernel(const u16* __restrict__ vb, u16* __restrict__ vt)
{
    __shared__ u16 t[64][65];
    const int blk = blockIdx.x;
    const int st = blk & 15, h = (blk >> 4) & 15, b = blk >> 8;
    const int tid = threadIdx.x;
#pragma unroll
    for (int p = 0; p < 16; ++p) {
        int idx = p * 256 + tid;
        int s = idx >> 6, d = idx & 63;
        t[s][d] = vb[(size_t)(b*SEQ + st*64 + s) * H_DIM + h*DH + d];
    }
    __syncthreads();
#pragma unroll
    for (int p = 0; p < 16; ++p) {
        int idx = p * 256 + tid;
        int d = idx >> 6, s = idx & 63;
        vt[(size_t)((b*NH + h)*DH + d) * SEQ + st*64 + s] = t[s][d];
    }
}

// ---------------- flash attention, S^T formulation + LDS-staged K/V ----------------
// Block = 64 q-rows of one (b,h); wave = 16 q-rows. K/V tiles (64x64) staged once
// per block into double-buffered LDS via global_load_lds (coalesced DMA), shared by
// all 4 waves; prefetch of tile j+1 overlaps compute of tile j (1 barrier/iter).
// XCD swizzle: all 16 qt-blocks of one (b,h) get ids congruent mod 8 -> same XCD L2.
__global__ __launch_bounds__(256, 3) void attn_kernel(
    const u16* __restrict__ qb, const u16* __restrict__ kb,
    const u16* __restrict__ vt, const float* __restrict__ mask,
    u16* __restrict__ ctx)
{
    __shared__ u16 Ks[2][64 * 64];     // 8KB per buffer
    __shared__ u16 Vs[2][64 * 64];     // 8KB per buffer
    __shared__ u16 plds[4][16 * 72];   // per-wave P^T tile, stride 72 u16

    // swizzle: raw = s*8 + xg; bh = xg + 8*(s>>4); qt = s&15  (bh%8 == raw%8)
    const int raw = blockIdx.x;
    const int xg = raw & 7, sg = raw >> 3;
    const int bh = xg + 8 * (sg >> 4);
    const int qt = sg & 15;
    const int b = bh >> 4, h = bh & 15;
    const int tid = threadIdx.x, w = tid >> 6, lane = tid & 63, q4 = lane >> 4, l16 = lane & 15;

    const u16* qrow = qb + ((size_t)(b*SEQ + qt*64 + w*16 + l16) * H_DIM + h*DH);
    bf16x8_t qf0 = *(const bf16x8_t*)(qrow + q4*8);
    bf16x8_t qf1 = *(const bf16x8_t*)(qrow + 32 + q4*8);

    const u16* kbp   = kb + ((size_t)(b*SEQ) * H_DIM + h*DH);   // K rows stride H_DIM
    const u16* vbase = vt + ((size_t)((b*NH + h)*DH) * SEQ);    // V^T rows stride SEQ
    const float* mrow = mask + b*SEQ;

    // staging coords: 2 rounds x 256 threads x 16B; chunk c -> row c>>3, elem (c&7)*8
    const int srow0 = tid >> 3;            // rows 0..31
    const int srow1 = 32 + (tid >> 3);     // rows 32..63
    const int sel   = (tid & 7) * 8;
    const int ldsb0 = w * 512;             // halves; round 0 wave base
    const int ldsb1 = 2048 + w * 512;      // round 1 wave base

    f32x4_t o[4];
#pragma unroll
    for (int dt = 0; dt < 4; ++dt) o[dt] = (f32x4_t){0.f,0.f,0.f,0.f};
    float mi = -1e30f, li = 0.f;
    u16* pw = &plds[w][0];

    // preload tile 0
    gld16(kbp + (size_t)srow0 * H_DIM + sel, &Ks[0][ldsb0]);
    gld16(kbp + (size_t)srow1 * H_DIM + sel, &Ks[0][ldsb1]);
    gld16(vbase + (size_t)srow0 * SEQ + sel, &Vs[0][ldsb0]);
    gld16(vbase + (size_t)srow1 * SEQ + sel, &Vs[0][ldsb1]);
    __syncthreads();

    for (int j = 0; j < 16; ++j) {
        const int kb0 = j * 64;
        const int buf = j & 1, nxt = buf ^ 1;
        // async prefetch of tile j+1 (in flight across whole compute below)
        if (j < 15) {
            const u16* gK = kbp + (size_t)(kb0 + 64) * H_DIM;
            const u16* gV = vbase + (kb0 + 64);
            gld16(gK + (size_t)srow0 * H_DIM + sel, &Ks[nxt][ldsb0]);
            gld16(gK + (size_t)srow1 * H_DIM + sel, &Ks[nxt][ldsb1]);
            gld16(gV + (size_t)srow0 * SEQ + sel, &Vs[nxt][ldsb0]);
            gld16(gV + (size_t)srow1 * SEQ + sel, &Vs[nxt][ldsb1]);
        }

        // S^T tile: row=key (block nt, q4*4+r), col=q (l16)
        f32x4_t sc[4];
#pragma unroll
        for (int nt = 0; nt < 4; ++nt) {
            bf16x8_t kf0 = *(const bf16x8_t*)&Ks[buf][(nt*16 + l16)*64 + q4*8];
            bf16x8_t kf1 = *(const bf16x8_t*)&Ks[buf][(nt*16 + l16)*64 + 32 + q4*8];
            f32x4_t s = (f32x4_t){0.f,0.f,0.f,0.f};
            s = __builtin_amdgcn_mfma_f32_16x16x32_bf16(kf0, qf0, s, 0, 0, 0);
            s = __builtin_amdgcn_mfma_f32_16x16x32_bf16(kf1, qf1, s, 0, 0, 0);
            f32x4_t mv = *(const f32x4_t*)&mrow[kb0 + nt*16 + q4*4];
#pragma unroll
            for (int r = 0; r < 4; ++r) s[r] += mv[r];
            sc[nt] = s;
        }
        // per-thread softmax over 16 keys + 2-shfl cross-q4 reduction
        float tmax = sc[0][0];
#pragma unroll
        for (int nt = 0; nt < 4; ++nt)
#pragma unroll
            for (int r = 0; r < 4; ++r) tmax = fmaxf(tmax, sc[nt][r]);
        tmax = fmaxf(tmax, __shfl_xor(tmax, 16));
        tmax = fmaxf(tmax, __shfl_xor(tmax, 32));
        float nm = fmaxf(mi, tmax);
        float al = __expf(mi - nm);
        mi = nm;
        float rs = 0.f;
#pragma unroll
        for (int nt = 0; nt < 4; ++nt)
#pragma unroll
            for (int r = 0; r < 4; ++r) {
                float p = __expf(sc[nt][r] - nm);
                sc[nt][r] = p; rs += p;
            }
        rs += __shfl_xor(rs, 16);
        rs += __shfl_xor(rs, 32);
        li = li * al + rs;
#pragma unroll
        for (int dt = 0; dt < 4; ++dt)
#pragma unroll
            for (int r = 0; r < 4; ++r) o[dt][r] *= al;

        // P^T -> per-wave LDS (row q=l16), wave-local ordering only
#pragma unroll
        for (int nt = 0; nt < 4; ++nt) {
            u16x4_t pb;
#pragma unroll
            for (int r = 0; r < 4; ++r) pb[r] = f2bf(sc[nt][r]);
            *(u16x4_t*)&pw[l16*72 + nt*16 + q4*4] = pb;
        }
        asm volatile("s_waitcnt lgkmcnt(0)" ::: "memory");
        bf16x8_t pf0 = *(const bf16x8_t*)&pw[l16*72 + q4*8];
        bf16x8_t pf1 = *(const bf16x8_t*)&pw[l16*72 + 32 + q4*8];
#pragma unroll
        for (int dt = 0; dt < 4; ++dt) {
            bf16x8_t vf0 = *(const bf16x8_t*)&Vs[buf][(dt*16 + l16)*64 + q4*8];
            bf16x8_t vf1 = *(const bf16x8_t*)&Vs[buf][(dt*16 + l16)*64 + 32 + q4*8];
            o[dt] = __builtin_amdgcn_mfma_f32_16x16x32_bf16(vf0, pf0, o[dt], 0, 0, 0);
            o[dt] = __builtin_amdgcn_mfma_f32_16x16x32_bf16(vf1, pf1, o[dt], 0, 0, 0);
        }
        // barrier: waves done reading buf; own DMA into nxt drained (compiler
        // emits vmcnt(0) lgkmcnt(0) before s_barrier)
        if (j < 15) __syncthreads();
    }
    const float inv = 1.0f / li;
    const size_t tokbase = (size_t)(b*SEQ + qt*64 + w*16 + l16) * H_DIM + h*DH;
#pragma unroll
    for (int dt = 0; dt < 4; ++dt) {
        u16x4_t ob;
#pragma unroll
        for (int r = 0; r < 4; ++r) ob[r] = f2bf(o[dt][r] * inv);
        *(u16x4_t*)&ctx[tokbase + dt*16 + q4*4] = ob;
    }
}

// ---------------- RMSNorm row kernel: outf = v*rsqrt(mean(v^2)+eps)*g (+ bf16 copy) ----------------
__global__ void rms_kernel(const float* __restrict__ in, const float* __restrict__ g,
                           float* __restrict__ outf, u16* __restrict__ outb)
{
    int row  = blockIdx.x * 4 + (threadIdx.x >> 6);
    int lane = threadIdx.x & 63;
    const f32x4_t* ip = (const f32x4_t*)(in + (size_t)row * H_DIM);
    f32x4_t v[4];
    float ss = 0.f;
#pragma unroll
    for (int k = 0; k < 4; ++k) {
        v[k] = ip[k * 64 + lane];
#pragma unroll
        for (int e = 0; e < 4; ++e) ss += v[k][e] * v[k][e];
    }
#pragma unroll
    for (int m = 32; m; m >>= 1) ss += __shfl_xor(ss, m);
    float sc = rsqrtf(ss * (1.0f / 1024.0f) + 1e-6f);
#pragma unroll
    for (int k = 0; k < 4; ++k) {
        f32x4_t gv = ((const f32x4_t*)g)[k * 64 + lane];
        f32x4_t ov;
        u16x4_t ob;
#pragma unroll
        for (int e = 0; e < 4; ++e) { ov[e] = v[k][e] * sc * gv[e]; ob[e] = f2bf(ov[e]); }
        if (outf) ((f32x4_t*)(outf + (size_t)row * H_DIM))[k * 64 + lane] = ov;
        if (outb) ((u16x4_t*)(outb + (size_t)row * H_DIM))[k * 64 + lane] = ob;
    }
}

extern "C" void kernel_launch(void* const* d_in, const int* in_sizes, int n_in,
                              void* d_out, int out_size, void* d_ws, size_t ws_size,
                              hipStream_t stream)
{
    const float* x   = (const float*)d_in[0];
    const float* y   = (const float*)d_in[1];
    const float* mask= (const float*)d_in[2];
    const float* Wq  = (const float*)d_in[3];
    const float* bq  = (const float*)d_in[4];
    const float* Wk  = (const float*)d_in[5];
    const float* bk  = (const float*)d_in[6];
    const float* Wv  = (const float*)d_in[7];
    const float* bv  = (const float*)d_in[8];
    const float* Wo  = (const float*)d_in[9];
    const float* bo  = (const float*)d_in[10];
    const float* g1  = (const float*)d_in[11];
    const float* Wi  = (const float*)d_in[12];
    const float* bi  = (const float*)d_in[13];
    const float* Wo2 = (const float*)d_in[14];
    const float* bo2 = (const float*)d_in[15];
    const float* g2  = (const float*)d_in[16];
    const int*   tp  = (const int*)d_in[17];
    float* out = (float*)d_out;

    char* ws = (char*)d_ws;
    const size_t MB = 1024 * 1024;
    float* c1    = (float*)(ws);
    float* c2    = (float*)(ws + 16 * 1024);
    float* bkv   = (float*)(ws + 32 * 1024);   // packed bk||bv (2048 f32)
    u16* xs_b    = (u16*)(ws + 1 * MB);    // 8MB; reused as ctx_b after QKV
    u16* ys_b    = (u16*)(ws + 9 * MB);    // 8MB; reused as att_b after V GEMM
    u16* wq_t    = (u16*)(ws + 17 * MB);
    u16* wk_t    = (u16*)(ws + 19 * MB);   // wk_t and wv_t contiguous: fused KV weight
    u16* wv_t    = (u16*)(ws + 21 * MB);
    u16* wo_t    = (u16*)(ws + 23 * MB);
    u16* wi_t    = (u16*)(ws + 25 * MB);   // 8MB
    u16* wo2_t   = (u16*)(ws + 33 * MB);   // 8MB
    u16* qb      = (u16*)(ws + 41 * MB);   // 8MB, reused as inter_b after attention
    u16* kb      = (u16*)(ws + 49 * MB);   // 8MB, kb/vb contiguous: fused KV output
    u16* vb      = (u16*)(ws + 57 * MB);   // 8MB
    u16* vtb     = (u16*)(ws + 65 * MB);   // 8MB
    u16* inter_b = qb;
    float* attpre= (float*)(ws + 73 * MB); // 16MB; reused as ffn2 out
    float* attf  = (float*)(ws + 89 * MB); // 16MB
    (void)ws_size; (void)in_sizes; (void)n_in; (void)out_size; (void)wv_t; (void)vb;

    route_scale_kernel<<<1024, 256, 0, stream>>>(x, y, tp, c1, c2, xs_b, ys_b);
    pack2_kernel<<<8, 256, 0, stream>>>(bk, bv, bkv);
    wcast4_kernel<<<4096, 256, 0, stream>>>(Wq, Wk, Wv, Wo, wq_t, wk_t, wv_t, wo_t);
    wcast_kernel<<<4096, 256, 0, stream>>>(Wi, wi_t, 1024, 4096);
    wcast_kernel<<<4096, 256, 0, stream>>>(Wo2, wo2_t, 4096, 1024);

    // Q projection (1/sqrt(DH)=0.125 folded), N=1024, BN=64 -> 512 blocks
    gemm_bt<64><<<512, 256, 0, stream>>>(xs_b, wq_t, 1024, 1024, bq, 0.125f, 0, qb, nullptr, nullptr, nullptr);
    // Fused K+V projection: Bt = [wk_t;wv_t] (2048x1024), out split to kb/vb -> 512 blocks
    gemm_bt<128><<<512, 256, 0, stream>>>(ys_b, wk_t, 2048, 1024, bkv, 1.0f, 0, kb, nullptr, nullptr, nullptr);
    vtrans_kernel<<<1024, 256, 0, stream>>>(vb, vtb);
    attn_kernel<<<1024, 256, 0, stream>>>(qb, kb, vtb, mask, xs_b /*ctx*/);
    // Wo projection + bias + xs residual (xs = c1*x recomputed in f32)
    gemm_bt<64><<<512, 256, 0, stream>>>(xs_b, wo_t, 1024, 1024, bo, 1.0f, 1, nullptr, attpre, c1, x);
    rms_kernel<<<1024, 256, 0, stream>>>(attpre, g1, attf, ys_b /*att_b*/);
    // FFN up + exact GELU, N=4096 -> 1024 blocks
    gemm_bt<128><<<1024, 256, 0, stream>>>(ys_b, wi_t, 4096, 1024, bi, 1.0f, 2, inter_b, nullptr, nullptr, nullptr);
    // FFN down + bias + att residual, N=1024, K=4096, BN=64 -> 512 blocks
    gemm_bt<64><<<512, 256, 0, stream>>>(inter_b, wo2_t, 1024, 4096, bo2, 1.0f, 1, nullptr, attpre, nullptr, attf);
    rms_kernel<<<1024, 256, 0, stream>>>(attpre, g2, out, nullptr);
}

// Round 6
// 445.374 us; speedup vs baseline: 1.5020x; 1.0611x over previous
//
#include <hip/hip_runtime.h>

typedef unsigned short u16;
typedef __attribute__((ext_vector_type(8))) short bf16x8_t;   // 8 bf16 (4 VGPRs)
typedef __attribute__((ext_vector_type(4))) float f32x4_t;
typedef __attribute__((ext_vector_type(4))) unsigned short u16x4_t;

#define H_DIM 1024
#define NH 16
#define DH 64
#define I_DIM 4096
#define BATCH 4
#define SEQ 1024
#define M_ROWS 4096   /* BATCH*SEQ */

__device__ __forceinline__ u16 f2bf(float f) {
    unsigned int u = __builtin_bit_cast(unsigned int, f);
    u += 0x7fffu + ((u >> 16) & 1u);
    return (u16)(u >> 16);
}
__device__ __forceinline__ float bf2f(u16 b) {
    unsigned int u = ((unsigned int)b) << 16;
    return __builtin_bit_cast(float, u);
}

__device__ __forceinline__ void gld16(const void* g, void* l) {
    __builtin_amdgcn_global_load_lds(
        (const __attribute__((address_space(1))) unsigned int*)g,
        (__attribute__((address_space(3))) unsigned int*)l,
        16, 0, 0);
}

// ------- fused routing + scale/cast: Gram dots -> t-loop -> xs=bf16(c1*x), ys=bf16(c2*y) -------
__global__ void route_scale_kernel(const float* __restrict__ x, const float* __restrict__ y,
                                   const int* __restrict__ tptr,
                                   float* __restrict__ c1o, float* __restrict__ c2o,
                                   u16* __restrict__ xs, u16* __restrict__ ys)
{
    int tok  = blockIdx.x * 4 + (threadIdx.x >> 6);
    int lane = threadIdx.x & 63;
    const f32x4_t* xp = (const f32x4_t*)(x + (size_t)tok * H_DIM);
    const f32x4_t* yp = (const f32x4_t*)(y + (size_t)tok * H_DIM);
    f32x4_t xv[4], yv[4];
    float xx = 0.f, xy = 0.f, yy = 0.f;
#pragma unroll
    for (int k = 0; k < 4; ++k) {
        xv[k] = xp[k * 64 + lane]; yv[k] = yp[k * 64 + lane];
#pragma unroll
        for (int e = 0; e < 4; ++e) {
            xx += xv[k][e]*xv[k][e]; xy += xv[k][e]*yv[k][e]; yy += yv[k][e]*yv[k][e];
        }
    }
#pragma unroll
    for (int m = 32; m; m >>= 1) {
        xx += __shfl_xor(xx, m); xy += __shfl_xor(xy, m); yy += __shfl_xor(yy, m);
    }
    int T = tptr[0];
    float c1 = 0.5f, c2 = 0.5f, b1 = 0.f, b2 = 0.f;
    for (int i = 0; i < T; ++i) {
        if (i > 0) {
            float mx = fmaxf(b1, b2);
            float e1 = __expf(b1 - mx), e2 = __expf(b2 - mx);
            float inv = 1.0f / (e1 + e2);
            c1 = e1 * inv; c2 = e2 * inv;
        }
        float vv = c1*c1*xx + 2.0f*c1*c2*xy + c2*c2*yy;
        float n  = sqrtf(vv);
        float s  = n / (1.0f + vv);            // n/(1+n^2), n^2 == vv
        float d1 = s * (c1*xx + c2*xy);
        float d2 = s * (c1*xy + c2*yy);
        b1 += d1; b2 += d2;
    }
    if (lane == 0) { c1o[tok] = c1; c2o[tok] = c2; }
#pragma unroll
    for (int k = 0; k < 4; ++k) {
        u16x4_t xo, yo;
#pragma unroll
        for (int e = 0; e < 4; ++e) { xo[e] = f2bf(xv[k][e]*c1); yo[e] = f2bf(yv[k][e]*c2); }
        ((u16x4_t*)(xs + (size_t)tok * H_DIM))[k * 64 + lane] = xo;
        ((u16x4_t*)(ys + (size_t)tok * H_DIM))[k * 64 + lane] = yo;
    }
}

// ---------------- pack two 1024-bias vectors into one 2048 buffer ----------------
__global__ void pack2_kernel(const float* __restrict__ a, const float* __restrict__ b,
                             float* __restrict__ o)
{
    int i = blockIdx.x * 256 + threadIdx.x;   // 0..2047
    o[i] = (i < 1024) ? a[i] : b[i - 1024];
}

// ---------------- W (Kw x Nw) f32 -> W^T (Nw x Kw) bf16 ----------------
__device__ __forceinline__ void wcast_body(const float* __restrict__ W, u16* __restrict__ Wt,
                                           int Kw, int Nw, int blk, int tid, float* t /*32x33*/)
{
    int nbj = Nw >> 5;
    int bi = blk / nbj, bj = blk % nbj;
#pragma unroll
    for (int p = 0; p < 4; ++p) {
        int idx = p * 256 + tid;
        int r = idx >> 5, c = idx & 31;
        t[r * 33 + c] = W[(size_t)(bi*32 + r) * Nw + bj*32 + c];
    }
    __syncthreads();
#pragma unroll
    for (int p = 0; p < 4; ++p) {
        int idx = p * 256 + tid;
        int r = idx >> 5, c = idx & 31;
        Wt[(size_t)(bj*32 + r) * Kw + bi*32 + c] = f2bf(t[c * 33 + r]);
    }
}

__global__ void wcast_kernel(const float* __restrict__ W, u16* __restrict__ Wt, int Kw, int Nw)
{
    __shared__ float t[32 * 33];
    wcast_body(W, Wt, Kw, Nw, blockIdx.x, threadIdx.x, t);
}

// four H_DIMxH_DIM weights in one launch (4096 blocks)
__global__ void wcast4_kernel(const float* __restrict__ W0, const float* __restrict__ W1,
                              const float* __restrict__ W2, const float* __restrict__ W3,
                              u16* __restrict__ T0, u16* __restrict__ T1,
                              u16* __restrict__ T2, u16* __restrict__ T3)
{
    __shared__ float t[32 * 33];
    int which = blockIdx.x >> 10, blk = blockIdx.x & 1023;
    const float* W = (which == 0) ? W0 : (which == 1) ? W1 : (which == 2) ? W2 : W3;
    u16* Wt = (which == 0) ? T0 : (which == 1) ? T1 : (which == 2) ? T2 : T3;
    wcast_body(W, Wt, 1024, 1024, blk, threadIdx.x, t);
}

// ---------------- GEMM: C = A(M,K) @ Bt(N,K)^T, bf16 in, f32 accum ----------------
// All call sites have M=4096 -> ntM=32 -> 4 tm per XCD. Block swizzle gives each
// XCD a contiguous 4-tm x all-tn slab (balanced A/B L2 fills; see R5 post-mortem).
// epi 0: outb[(gcol>>10)*M*H + grow*H + (gcol&1023)] = bf16((acc+bias)*(gcol<1024?scale:1))
// epi 1: outf = acc + bias + bf16_resm[row,col]   (residual add, bf16 residual)
// epi 2: outb = bf16(gelu_tanh(acc+bias))
#define BK 64

template<int TBN>
__global__ __launch_bounds__(256, (TBN == 128) ? 3 : 4) void gemm_bt(
    const u16* __restrict__ A, const u16* __restrict__ Bt, int N, int K,
    const float* __restrict__ bias, float scale, int epi,
    u16* __restrict__ outb, float* __restrict__ outf,
    const u16* __restrict__ resm)
{
    constexpr int TBM = 128;
    constexpr int MT = (TBN == 128) ? 4 : 2;
    constexpr int NT = 4;
    __shared__ u16 As[TBM * BK];   // 16KB
    __shared__ u16 Bs[TBN * BK];   // 16KB or 8KB
    // XCD swizzle: xg = id&7 -> XCD; tm = xg*4 + (sg&3); tn = sg>>2
    const int xg = blockIdx.x & 7, sg = blockIdx.x >> 3;
    const int tm = xg * 4 + (sg & 3);
    const int tn = sg >> 2;
    const int tid = threadIdx.x;
    const int w = tid >> 6, lane = tid & 63, q4 = lane >> 4, l16 = lane & 15;
    const int wm = (TBN == 128) ? (w >> 1) * 64 : w * 32;
    const int wn = (TBN == 128) ? (w & 1) * 64 : 0;

    // staging map: chunk c covers rows c*32..c*32+31; thread -> row tid>>3, col (tid&7)*8
    const int srow = tid >> 3;
    const int scol = (tid & 7) * 8;
    const u16* ga = A  + (size_t)(tm * TBM + srow) * K + scol;
    const u16* gb = Bt + (size_t)(tn * TBN + srow) * K + scol;

    f32x4_t acc[MT][NT];
#pragma unroll
    for (int mt = 0; mt < MT; ++mt)
#pragma unroll
        for (int nt = 0; nt < NT; ++nt) acc[mt][nt] = (f32x4_t){0.f,0.f,0.f,0.f};

    for (int k0 = 0; k0 < K; k0 += BK) {
        __syncthreads();
#pragma unroll
        for (int c = 0; c < 4; ++c)
            gld16(ga + (size_t)c * 32 * K + k0, &As[c * 2048 + w * 512]);
#pragma unroll
        for (int c = 0; c < TBN/32; ++c)
            gld16(gb + (size_t)c * 32 * K + k0, &Bs[c * 2048 + w * 512]);
        __syncthreads();
#pragma unroll
        for (int kc = 0; kc < 2; ++kc) {
            bf16x8_t af[MT], bfr[NT];
#pragma unroll
            for (int mt = 0; mt < MT; ++mt)
                af[mt] = *(const bf16x8_t*)&As[(wm + mt*16 + l16) * BK + kc*32 + q4*8];
#pragma unroll
            for (int nt = 0; nt < NT; ++nt)
                bfr[nt] = *(const bf16x8_t*)&Bs[(wn + nt*16 + l16) * BK + kc*32 + q4*8];
#pragma unroll
            for (int mt = 0; mt < MT; ++mt)
#pragma unroll
                for (int nt = 0; nt < NT; ++nt)
                    acc[mt][nt] = __builtin_amdgcn_mfma_f32_16x16x32_bf16(af[mt], bfr[nt], acc[mt][nt], 0, 0, 0);
        }
    }

#pragma unroll
    for (int mt = 0; mt < MT; ++mt) {
#pragma unroll
        for (int nt = 0; nt < NT; ++nt) {
            const int gcol = tn * TBN + wn + nt*16 + l16;
            const float bv = bias[gcol];
#pragma unroll
            for (int r = 0; r < 4; ++r) {
                const int grow = tm * TBM + wm + mt*16 + q4*4 + r;
                float v = acc[mt][nt][r] + bv;
                if (epi == 0) {
                    float sc2 = (gcol < 1024) ? scale : 1.0f;
                    size_t o = (size_t)(gcol >> 10) * ((size_t)M_ROWS * H_DIM)
                             + (size_t)grow * H_DIM + (gcol & 1023);
                    outb[o] = f2bf(v * sc2);
                } else if (epi == 1) {
                    const size_t oidx = (size_t)grow * N + gcol;
                    outf[oidx] = v + bf2f(resm[oidx]);
                } else {
                    const size_t oidx = (size_t)grow * N + gcol;
                    // tanh-approx GELU (max dev ~1e-3 vs exact for |v|<4)
                    float z = 0.7978845608f * (v + 0.044715f * v * v * v);
                    float e = __expf(2.0f * z);
                    float th = 1.0f - 2.0f / (e + 1.0f);
                    outb[oidx] = f2bf(0.5f * v * (1.0f + th));
                }
            }
        }
    }
}

// ---------------- V (B,S,NH,DH) bf16 -> Vt (B,NH,DH,S) bf16 ----------------
__global__ void vtrans_kernel(const u16* __restrict__ vb, u16* __restrict__ vt)
{
    __shared__ u16 t[64][65];
    const int blk = blockIdx.x;
    const int st = blk & 15, h = (blk >> 4) & 15, b = blk >> 8;
    const int tid = threadIdx.x;
#pragma unroll
    for (int p = 0; p < 16; ++p) {
        int idx = p * 256 + tid;
        int s = idx >> 6, d = idx & 63;
        t[s][d] = vb[(size_t)(b*SEQ + st*64 + s) * H_DIM + h*DH + d];
    }
    __syncthreads();
#pragma unroll
    for (int p = 0; p < 16; ++p) {
        int idx = p * 256 + tid;
        int d = idx >> 6, s = idx & 63;
        vt[(size_t)((b*NH + h)*DH + d) * SEQ + st*64 + s] = t[s][d];
    }
}

// ---------------- flash attention, S^T formulation + LDS-staged K/V ----------------
__global__ __launch_bounds__(256, 3) void attn_kernel(
    const u16* __restrict__ qb, const u16* __restrict__ kb,
    const u16* __restrict__ vt, const float* __restrict__ mask,
    u16* __restrict__ ctx)
{
    __shared__ u16 Ks[2][64 * 64];     // 8KB per buffer
    __shared__ u16 Vs[2][64 * 64];     // 8KB per buffer
    __shared__ u16 plds[4][16 * 72];   // per-wave P^T tile, stride 72 u16

    // swizzle: raw = s*8 + xg; bh = xg + 8*(s>>4); qt = s&15  (bh%8 == raw%8)
    const int raw = blockIdx.x;
    const int xg = raw & 7, sg = raw >> 3;
    const int bh = xg + 8 * (sg >> 4);
    const int qt = sg & 15;
    const int b = bh >> 4, h = bh & 15;
    const int tid = threadIdx.x, w = tid >> 6, lane = tid & 63, q4 = lane >> 4, l16 = lane & 15;

    const u16* qrow = qb + ((size_t)(b*SEQ + qt*64 + w*16 + l16) * H_DIM + h*DH);
    bf16x8_t qf0 = *(const bf16x8_t*)(qrow + q4*8);
    bf16x8_t qf1 = *(const bf16x8_t*)(qrow + 32 + q4*8);

    const u16* kbp   = kb + ((size_t)(b*SEQ) * H_DIM + h*DH);   // K rows stride H_DIM
    const u16* vbase = vt + ((size_t)((b*NH + h)*DH) * SEQ);    // V^T rows stride SEQ
    const float* mrow = mask + b*SEQ;

    const int srow0 = tid >> 3;            // rows 0..31
    const int srow1 = 32 + (tid >> 3);     // rows 32..63
    const int sel   = (tid & 7) * 8;
    const int ldsb0 = w * 512;
    const int ldsb1 = 2048 + w * 512;

    f32x4_t o[4];
#pragma unroll
    for (int dt = 0; dt < 4; ++dt) o[dt] = (f32x4_t){0.f,0.f,0.f,0.f};
    float mi = -1e30f, li = 0.f;
    u16* pw = &plds[w][0];

    gld16(kbp + (size_t)srow0 * H_DIM + sel, &Ks[0][ldsb0]);
    gld16(kbp + (size_t)srow1 * H_DIM + sel, &Ks[0][ldsb1]);
    gld16(vbase + (size_t)srow0 * SEQ + sel, &Vs[0][ldsb0]);
    gld16(vbase + (size_t)srow1 * SEQ + sel, &Vs[0][ldsb1]);
    __syncthreads();

    for (int j = 0; j < 16; ++j) {
        const int kb0 = j * 64;
        const int buf = j & 1, nxt = buf ^ 1;
        if (j < 15) {
            const u16* gK = kbp + (size_t)(kb0 + 64) * H_DIM;
            const u16* gV = vbase + (kb0 + 64);
            gld16(gK + (size_t)srow0 * H_DIM + sel, &Ks[nxt][ldsb0]);
            gld16(gK + (size_t)srow1 * H_DIM + sel, &Ks[nxt][ldsb1]);
            gld16(gV + (size_t)srow0 * SEQ + sel, &Vs[nxt][ldsb0]);
            gld16(gV + (size_t)srow1 * SEQ + sel, &Vs[nxt][ldsb1]);
        }

        f32x4_t sc[4];
#pragma unroll
        for (int nt = 0; nt < 4; ++nt) {
            bf16x8_t kf0 = *(const bf16x8_t*)&Ks[buf][(nt*16 + l16)*64 + q4*8];
            bf16x8_t kf1 = *(const bf16x8_t*)&Ks[buf][(nt*16 + l16)*64 + 32 + q4*8];
            f32x4_t s = (f32x4_t){0.f,0.f,0.f,0.f};
            s = __builtin_amdgcn_mfma_f32_16x16x32_bf16(kf0, qf0, s, 0, 0, 0);
            s = __builtin_amdgcn_mfma_f32_16x16x32_bf16(kf1, qf1, s, 0, 0, 0);
            f32x4_t mv = *(const f32x4_t*)&mrow[kb0 + nt*16 + q4*4];
#pragma unroll
            for (int r = 0; r < 4; ++r) s[r] += mv[r];
            sc[nt] = s;
        }
        float tmax = sc[0][0];
#pragma unroll
        for (int nt = 0; nt < 4; ++nt)
#pragma unroll
            for (int r = 0; r < 4; ++r) tmax = fmaxf(tmax, sc[nt][r]);
        tmax = fmaxf(tmax, __shfl_xor(tmax, 16));
        tmax = fmaxf(tmax, __shfl_xor(tmax, 32));
        float nm = fmaxf(mi, tmax);
        float al = __expf(mi - nm);
        mi = nm;
        float rs = 0.f;
#pragma unroll
        for (int nt = 0; nt < 4; ++nt)
#pragma unroll
            for (int r = 0; r < 4; ++r) {
                float p = __expf(sc[nt][r] - nm);
                sc[nt][r] = p; rs += p;
            }
        rs += __shfl_xor(rs, 16);
        rs += __shfl_xor(rs, 32);
        li = li * al + rs;
#pragma unroll
        for (int dt = 0; dt < 4; ++dt)
#pragma unroll
            for (int r = 0; r < 4; ++r) o[dt][r] *= al;

#pragma unroll
        for (int nt = 0; nt < 4; ++nt) {
            u16x4_t pb;
#pragma unroll
            for (int r = 0; r < 4; ++r) pb[r] = f2bf(sc[nt][r]);
            *(u16x4_t*)&pw[l16*72 + nt*16 + q4*4] = pb;
        }
        asm volatile("s_waitcnt lgkmcnt(0)" ::: "memory");
        bf16x8_t pf0 = *(const bf16x8_t*)&pw[l16*72 + q4*8];
        bf16x8_t pf1 = *(const bf16x8_t*)&pw[l16*72 + 32 + q4*8];
#pragma unroll
        for (int dt = 0; dt < 4; ++dt) {
            bf16x8_t vf0 = *(const bf16x8_t*)&Vs[buf][(dt*16 + l16)*64 + q4*8];
            bf16x8_t vf1 = *(const bf16x8_t*)&Vs[buf][(dt*16 + l16)*64 + 32 + q4*8];
            o[dt] = __builtin_amdgcn_mfma_f32_16x16x32_bf16(vf0, pf0, o[dt], 0, 0, 0);
            o[dt] = __builtin_amdgcn_mfma_f32_16x16x32_bf16(vf1, pf1, o[dt], 0, 0, 0);
        }
        if (j < 15) __syncthreads();
    }
    const float inv = 1.0f / li;
    const size_t tokbase = (size_t)(b*SEQ + qt*64 + w*16 + l16) * H_DIM + h*DH;
#pragma unroll
    for (int dt = 0; dt < 4; ++dt) {
        u16x4_t ob;
#pragma unroll
        for (int r = 0; r < 4; ++r) ob[r] = f2bf(o[dt][r] * inv);
        *(u16x4_t*)&ctx[tokbase + dt*16 + q4*4] = ob;
    }
}

// ---------------- RMSNorm row kernel: out = v*rsqrt(mean(v^2)+eps)*g ----------------
__global__ void rms_kernel(const float* __restrict__ in, const float* __restrict__ g,
                           float* __restrict__ outf, u16* __restrict__ outb)
{
    int row  = blockIdx.x * 4 + (threadIdx.x >> 6);
    int lane = threadIdx.x & 63;
    const f32x4_t* ip = (const f32x4_t*)(in + (size_t)row * H_DIM);
    f32x4_t v[4];
    float ss = 0.f;
#pragma unroll
    for (int k = 0; k < 4; ++k) {
        v[k] = ip[k * 64 + lane];
#pragma unroll
        for (int e = 0; e < 4; ++e) ss += v[k][e] * v[k][e];
    }
#pragma unroll
    for (int m = 32; m; m >>= 1) ss += __shfl_xor(ss, m);
    float sc = rsqrtf(ss * (1.0f / 1024.0f) + 1e-6f);
#pragma unroll
    for (int k = 0; k < 4; ++k) {
        f32x4_t gv = ((const f32x4_t*)g)[k * 64 + lane];
        f32x4_t ov;
        u16x4_t ob;
#pragma unroll
        for (int e = 0; e < 4; ++e) { ov[e] = v[k][e] * sc * gv[e]; ob[e] = f2bf(ov[e]); }
        if (outf) ((f32x4_t*)(outf + (size_t)row * H_DIM))[k * 64 + lane] = ov;
        if (outb) ((u16x4_t*)(outb + (size_t)row * H_DIM))[k * 64 + lane] = ob;
    }
}

extern "C" void kernel_launch(void* const* d_in, const int* in_sizes, int n_in,
                              void* d_out, int out_size, void* d_ws, size_t ws_size,
                              hipStream_t stream)
{
    const float* x   = (const float*)d_in[0];
    const float* y   = (const float*)d_in[1];
    const float* mask= (const float*)d_in[2];
    const float* Wq  = (const float*)d_in[3];
    const float* bq  = (const float*)d_in[4];
    const float* Wk  = (const float*)d_in[5];
    const float* bk  = (const float*)d_in[6];
    const float* Wv  = (const float*)d_in[7];
    const float* bv  = (const float*)d_in[8];
    const float* Wo  = (const float*)d_in[9];
    const float* bo  = (const float*)d_in[10];
    const float* g1  = (const float*)d_in[11];
    const float* Wi  = (const float*)d_in[12];
    const float* bi  = (const float*)d_in[13];
    const float* Wo2 = (const float*)d_in[14];
    const float* bo2 = (const float*)d_in[15];
    const float* g2  = (const float*)d_in[16];
    const int*   tp  = (const int*)d_in[17];
    float* out = (float*)d_out;

    char* ws = (char*)d_ws;
    const size_t MB = 1024 * 1024;
    float* c1    = (float*)(ws);
    float* c2    = (float*)(ws + 16 * 1024);
    float* bkv   = (float*)(ws + 32 * 1024);   // packed bk||bv (2048 f32)
    u16* xs_b    = (u16*)(ws + 1 * MB);    // 8MB; stays live (Wo residual)
    u16* ys_b    = (u16*)(ws + 9 * MB);    // 8MB; reused as att_b after KV GEMM
    u16* wq_t    = (u16*)(ws + 17 * MB);
    u16* wk_t    = (u16*)(ws + 19 * MB);   // wk_t and wv_t contiguous: fused KV weight
    u16* wv_t    = (u16*)(ws + 21 * MB);
    u16* wo_t    = (u16*)(ws + 23 * MB);
    u16* wi_t    = (u16*)(ws + 25 * MB);   // 8MB
    u16* wo2_t   = (u16*)(ws + 33 * MB);   // 8MB
    u16* qb      = (u16*)(ws + 41 * MB);   // 8MB, reused as inter_b after attention
    u16* kb      = (u16*)(ws + 49 * MB);   // 8MB, kb/vb contiguous: fused KV output
    u16* vb      = (u16*)(ws + 57 * MB);   // 8MB
    u16* vtb     = (u16*)(ws + 65 * MB);   // 8MB
    u16* inter_b = qb;
    float* attpre= (float*)(ws + 73 * MB); // 16MB; reused as ffn2 pre-RMS out
    u16* ctx_b   = (u16*)(ws + 89 * MB);   // 8MB attention context
    (void)ws_size; (void)in_sizes; (void)n_in; (void)out_size; (void)wv_t; (void)vb; (void)c2;

    route_scale_kernel<<<1024, 256, 0, stream>>>(x, y, tp, c1, c2, xs_b, ys_b);
    pack2_kernel<<<8, 256, 0, stream>>>(bk, bv, bkv);
    wcast4_kernel<<<4096, 256, 0, stream>>>(Wq, Wk, Wv, Wo, wq_t, wk_t, wv_t, wo_t);
    wcast_kernel<<<4096, 256, 0, stream>>>(Wi, wi_t, 1024, 4096);
    wcast_kernel<<<4096, 256, 0, stream>>>(Wo2, wo2_t, 4096, 1024);

    // Q projection (1/sqrt(DH)=0.125 folded), N=1024, BN=64 -> 512 blocks
    gemm_bt<64><<<512, 256, 0, stream>>>(xs_b, wq_t, 1024, 1024, bq, 0.125f, 0, qb, nullptr, nullptr);
    // Fused K+V projection: Bt = [wk_t;wv_t] (2048x1024), out split to kb/vb -> 512 blocks
    gemm_bt<128><<<512, 256, 0, stream>>>(ys_b, wk_t, 2048, 1024, bkv, 1.0f, 0, kb, nullptr, nullptr);
    vtrans_kernel<<<1024, 256, 0, stream>>>(vb, vtb);
    attn_kernel<<<1024, 256, 0, stream>>>(qb, kb, vtb, mask, ctx_b);
    // Wo projection + bias + xs residual (bf16 residual from xs_b)
    gemm_bt<64><<<512, 256, 0, stream>>>(ctx_b, wo_t, 1024, 1024, bo, 1.0f, 1, nullptr, attpre, xs_b);
    rms_kernel<<<1024, 256, 0, stream>>>(attpre, g1, nullptr, ys_b /*att_b*/);
    // FFN up + tanh-approx GELU, N=4096 -> 1024 blocks
    gemm_bt<128><<<1024, 256, 0, stream>>>(ys_b, wi_t, 4096, 1024, bi, 1.0f, 2, inter_b, nullptr, nullptr);
    // FFN down + bias + att residual (bf16 residual from att_b)
    gemm_bt<64><<<512, 256, 0, stream>>>(inter_b, wo2_t, 1024, 4096, bo2, 1.0f, 1, nullptr, attpre, ys_b);
    rms_kernel<<<1024, 256, 0, stream>>>(attpre, g2, out, nullptr);
}